// Round 3
// baseline (484.841 us; speedup 1.0000x reference)
//
#include <hip/hip_runtime.h>
#include <hip/hip_cooperative_groups.h>
#include <math.h>

namespace cg = cooperative_groups;

// Shapes fixed by the reference: B=2, N=32, L=4, ED=64, H=4, HD=16
#define EPS 1e-5f

struct Params {
    const int* ei; const int* batch; int E;
    const float* W0; const float* b0; const float* Ws; const float* bs;
    const float* ln_g; const float* ln_b;
    const float* fW0; const float* fb0; const float* fWs; const float* fbs;
    const float* fln_g; const float* fln_b;
    const float* opW; const float* opb;
    float* adj;   // 2048
    float* x;     // 131072  (B,N,N,ED)
    float* h;     // 131072
    float* q;     // 131072
    float* pmin;  // 4 layers * 4096  (bn in [0,64), e in [0,64))
    float* poff;  // 4 * 4096
    float* pdiag; // 4 * 4096
    float* out;   // 64
};

// One cooperative kernel for the whole network.
// Grid: 256 blocks x 512 threads = 131072 threads = one per (row, channel).
// Block covers 8 consecutive rows => same (b, xi) slab for the attn phase.
__launch_bounds__(512, 1)
__global__ void fused_all(Params p) {
    cg::grid_group grid = cg::this_grid();
    const int tid  = threadIdx.x;          // 0..511
    const int blk  = blockIdx.x;           // 0..255
    const int gtid = blk * 512 + tid;      // 0..131071

    const int row = gtid >> 6;             // 0..2047  = (b*32+xi)*32 + y
    const int c   = gtid & 63;             // channel = h*16 + d
    const int d   = c & 15;
    const int rl  = tid >> 6;              // row-in-block 0..7
    const int y   = row & 31;
    const int b   = row >> 10;

    const int r0     = blk * 8;
    const int b_blk  = r0 >> 10;
    const int xi_blk = (r0 >> 5) & 31;

    __shared__ float qx_s[2048];           // q rows (b_blk, xi_blk, a=0..31)
    __shared__ float hx_s[2048];           // h rows (same slab)
    __shared__ float xs[8][64];            // layer-input rows (fin + lin staging)
    __shared__ float xu_s[8][64];          // attn output per row
    __shared__ float rmx[128], rmn[128];   // final-phase scratch
    __shared__ float pooled_s[256];        // 2 graphs x 128
    __shared__ float scores_s[64];

    // ---- adjacency (block 0 only; internally ordered by __syncthreads) ----
    if (blk == 0) {
        for (int i2 = tid; i2 < 2048; i2 += 512) p.adj[i2] = 0.0f;
        __syncthreads();
        for (int e = tid; e < p.E; e += 512) {
            int e0 = p.ei[e], e1 = p.ei[p.E + e];
            int g  = p.batch[e0];
            atomicAdd(&p.adj[(g * 32 + (e0 - g * 32)) * 32 + (e1 - g * 32)], 1.0f);
        }
        __syncthreads();
        if (tid < 64) {
            int bb = tid >> 5, nn = tid & 31;
            p.adj[(bb * 32 + nn) * 32 + nn] = 2.0f;
        }
    }
    grid.sync();

    for (int layer = 0; layer < 4; ++layer) {
        const float* W     = layer == 0 ? p.W0  : p.Ws  + (layer - 1) * 4096;
        const float* bw    = layer == 0 ? p.b0  : p.bs  + (layer - 1) * 64;
        const float* fW    = layer == 0 ? p.fW0 : p.fWs + (layer - 1) * 8192;
        const float* fb    = layer == 0 ? p.fb0 : p.fbs + (layer - 1) * 64;
        const float* lg    = p.ln_g  + layer * 16;
        const float* lb    = p.ln_b  + layer * 16;
        const float* fg    = p.fln_g + layer * 64;
        const float* fbeta = p.fln_b + layer * 64;
        const int Cin = layer == 0 ? 1 : 64;

        // Pool partials for the PREVIOUS layer's output x. 4096 slots:
        // bn = (b*32+n) in [0,64), e in [0,64). Pure reads of x; the
        // grid.sync at the end of the previous iteration ordered x's write.
        if (layer > 0 && gtid < 4096) {
            int bn = gtid >> 6, e = gtid & 63;
            int nn = bn & 31;
            const float* xp = p.x + bn * 2048 + e;
            float mn = 1e30f, off = -1e30f, dg = 0.0f;
            #pragma unroll
            for (int m2 = 0; m2 < 32; ++m2) {
                float v = xp[m2 * 64];
                mn = fminf(mn, v);
                if (m2 == nn) dg = v; else off = fmaxf(off, v);
            }
            int o = (layer - 1) * 4096 + gtid;
            p.pmin[o] = mn; p.poff[o] = off; p.pdiag[o] = dg;
        }

        // ---- Phase L: h = x @ W.T + b ; q = LN16(h) ----
        float acc;
        if (Cin == 1) {
            acc = fmaf(W[c], p.adj[row], bw[c]);
        } else {
            xs[rl][c] = p.x[row * 64 + c];
            __syncthreads();
            acc = bw[c];
            const float* Wr = W + c * 64;
            const float* xr = xs[rl];
            #pragma unroll
            for (int j = 0; j < 64; ++j) acc = fmaf(Wr[j], xr[j], acc);
        }
        p.h[gtid] = acc;
        float s1 = acc;
        #pragma unroll
        for (int m = 1; m < 16; m <<= 1) s1 += __shfl_xor(s1, m, 16);
        float mean = s1 * 0.0625f;
        float dv = acc - mean;
        float s2 = dv * dv;
        #pragma unroll
        for (int m = 1; m < 16; m <<= 1) s2 += __shfl_xor(s2, m, 16);
        p.q[gtid] = dv * rsqrtf(s2 * 0.0625f + EPS) * lg[d] + lb[d];
        grid.sync();

        // ---- Phase A: fused attention + concat-linear + LN64, in-place x ----
        {   // stage the (b_blk, xi_blk, *) q/h slab (2048 floats each)
            const float4* qsrc = (const float4*)(p.q + (b_blk * 1024 + xi_blk * 32) * 64);
            const float4* hsrc = (const float4*)(p.h + (b_blk * 1024 + xi_blk * 32) * 64);
            ((float4*)qx_s)[tid] = qsrc[tid];
            ((float4*)hx_s)[tid] = hsrc[tid];
            if (Cin == 1) { if (c == 0) xs[rl][0] = p.adj[row]; }
            else          xs[rl][c] = p.x[row * 64 + c];
        }
        __syncthreads();

        const float gl = lg[d], bl = lb[d];
        const float* qy_p = p.q + (b * 1024 + y) * 64 + c;  // + a*2048
        const float* hy_p = p.h + (b * 1024 + y) * 64 + c;
        float mrun = -1e30f, lrun = 0.0f, arun = 0.0f;
        for (int a = 0; a < 32; ++a) {
            float qx = qx_s[a * 64 + c];
            float qy = qy_p[a * 2048];
            float hx = hx_s[a * 64 + c];
            float hy = hy_p[a * 2048];
            float rdot = qx * qy;
            float pp   = hx * hy;
            float rsum = pp;
            float rsq  = pp * pp;
            // three INDEPENDENT 16-lane reductions, interleaved for ILP
            #pragma unroll
            for (int m = 1; m < 16; m <<= 1) {
                rdot += __shfl_xor(rdot, m, 16);
                rsum += __shfl_xor(rsum, m, 16);
                rsq  += __shfl_xor(rsq,  m, 16);
            }
            float s     = rdot * 0.25f;              // / sqrt(HD)
            float pmean = rsum * 0.0625f;
            float pvar  = rsq * 0.0625f - pmean * pmean;
            float nrm   = (pp - pmean) * rsqrtf(pvar + EPS) * gl;
            float nm  = fmaxf(mrun, s);
            float scl = __expf(mrun - nm);
            float e   = __expf(s - nm);
            lrun = lrun * scl + e;
            arun = arun * scl + e * nrm;
            mrun = nm;
        }
        xu_s[rl][c] = arun / lrun + bl;   // softmax weights sum to 1 -> +lb once
        __syncthreads();

        // fin: y = concat([x, xu]) @ fW.T + fb, then LN64
        int K = Cin + 64;
        const float* Wr2 = fW + c * K;
        float acc2 = fb[c];
        if (Cin == 1) {
            acc2 = fmaf(Wr2[0], xs[rl][0], acc2);
            #pragma unroll
            for (int j = 0; j < 64; ++j) acc2 = fmaf(Wr2[1 + j], xu_s[rl][j], acc2);
        } else {
            #pragma unroll
            for (int j = 0; j < 64; ++j) acc2 = fmaf(Wr2[j], xs[rl][j], acc2);
            #pragma unroll
            for (int j = 0; j < 64; ++j) acc2 = fmaf(Wr2[64 + j], xu_s[rl][j], acc2);
        }
        float t1 = acc2;
        #pragma unroll
        for (int m = 1; m < 64; m <<= 1) t1 += __shfl_xor(t1, m, 64);
        float mu = t1 * (1.0f / 64.0f);
        float dv2 = acc2 - mu;
        float t2 = dv2 * dv2;
        #pragma unroll
        for (int m = 1; m < 64; m <<= 1) t2 += __shfl_xor(t2, m, 64);
        p.x[gtid] = dv2 * rsqrtf(t2 * (1.0f / 64.0f) + EPS) * fg[c] + fbeta[c];
        grid.sync();
    }

    // pool partials for layer 3 (all 4096 (bn,e) slots)
    if (gtid < 4096) {
        int bn = gtid >> 6, e = gtid & 63;
        int nn = bn & 31;
        const float* xp = p.x + bn * 2048 + e;
        float mn = 1e30f, off = -1e30f, dg = 0.0f;
        #pragma unroll
        for (int m2 = 0; m2 < 32; ++m2) {
            float v = xp[m2 * 64];
            mn = fminf(mn, v);
            if (m2 == nn) dg = v; else off = fmaxf(off, v);
        }
        int o = 3 * 4096 + gtid;
        p.pmin[o] = mn; p.poff[o] = off; p.pdiag[o] = dg;
    }
    grid.sync();

    // ---- final: pool finish + score GEMV + batchnorm (block 0) ----
    if (blk == 0) {
        if (tid < 64) scores_s[tid] = 0.0f;
        __syncthreads();
        for (int l = 0; l < 4; ++l) {
            float mn = 1e30f, off = -1e30f, dg = -1e30f;
            if (tid < 128) {
                int bb = tid >> 6, e = tid & 63;
                for (int nn = 0; nn < 32; ++nn) {
                    int idx = l * 4096 + (bb * 32 + nn) * 64 + e;
                    mn  = fminf(mn,  p.pmin[idx]);
                    off = fmaxf(off, p.poff[idx]);
                    dg  = fmaxf(dg,  p.pdiag[idx]);
                }
                rmx[tid] = dg; rmn[tid] = mn;
            }
            __syncthreads();
            if (tid == 0) {
                float gmx = -1e30f, gmn = 1e30f;
                for (int i2 = 0; i2 < 128; ++i2) {
                    gmx = fmaxf(gmx, rmx[i2]);
                    gmn = fminf(gmn, rmn[i2]);
                }
                rmx[0] = fabsf(gmx - gmn);   // |max_diag_global + max(-x)|
            }
            __syncthreads();
            float val = rmx[0];
            if (tid < 128) {
                int bb = tid >> 6, e = tid & 63;
                pooled_s[bb * 128 + e]      = dg;
                pooled_s[bb * 128 + 64 + e] = fmaxf(off, dg - val);
            }
            __syncthreads();
            if (tid < 64) {
                int bb = tid >> 5, cc = tid & 31;
                const float* Wr = p.opW + l * 4096 + cc * 128;
                float a2 = p.opb[l * 32 + cc];
                for (int j = 0; j < 128; ++j) a2 = fmaf(Wr[j], pooled_s[bb * 128 + j], a2);
                scores_s[tid] += a2;
            }
            __syncthreads();
        }
        if (tid < 32) {
            float sA = scores_s[tid], sB = scores_s[32 + tid];
            float mu = 0.5f * (sA + sB);
            float va = 0.5f * ((sA - mu) * (sA - mu) + (sB - mu) * (sB - mu));
            float inv = rsqrtf(va + EPS);
            p.out[tid]      = (sA - mu) * inv;
            p.out[32 + tid] = (sB - mu) * inv;
        }
    }
}

extern "C" void kernel_launch(void* const* d_in, const int* in_sizes, int n_in,
                              void* d_out, int out_size, void* d_ws, size_t ws_size,
                              hipStream_t stream) {
    Params prm;
    prm.ei    = (const int*)d_in[0];
    prm.batch = (const int*)d_in[1];
    prm.E     = in_sizes[0] / 2;
    prm.W0    = (const float*)d_in[2];
    prm.b0    = (const float*)d_in[3];
    prm.Ws    = (const float*)d_in[4];
    prm.bs    = (const float*)d_in[5];
    prm.ln_g  = (const float*)d_in[6];
    prm.ln_b  = (const float*)d_in[7];
    prm.fW0   = (const float*)d_in[8];
    prm.fb0   = (const float*)d_in[9];
    prm.fWs   = (const float*)d_in[10];
    prm.fbs   = (const float*)d_in[11];
    prm.fln_g = (const float*)d_in[12];
    prm.fln_b = (const float*)d_in[13];
    prm.opW   = (const float*)d_in[14];
    prm.opb   = (const float*)d_in[15];

    float* ws  = (float*)d_ws;
    prm.adj    = ws;                    // 2048
    prm.x      = prm.adj   + 2048;      // 131072
    prm.h      = prm.x     + 131072;    // 131072
    prm.q      = prm.h     + 131072;    // 131072
    prm.pmin   = prm.q     + 131072;    // 4*4096
    prm.poff   = prm.pmin  + 16384;     // 4*4096
    prm.pdiag  = prm.poff  + 16384;     // 4*4096
    prm.out    = (float*)d_out;

    void* args[] = { &prm };
    hipLaunchCooperativeKernel((void*)fused_all, dim3(256), dim3(512), args, 0, stream);
}

// Round 4
// 305.151 us; speedup vs baseline: 1.5889x; 1.5889x over previous
//
#include <hip/hip_runtime.h>
#include <math.h>

// Shapes fixed by the reference: B=2, N=32, L=4, ED=64, H=4, HD=16
#define EPS 1e-5f
#define NBLK 256
#define MAGIC 0x13579BDF

struct Params {
    const int* ei; const int* batch; int E;
    const float* W0; const float* b0; const float* Ws; const float* bs;
    const float* ln_g; const float* ln_b;
    const float* fW0; const float* fb0; const float* fWs; const float* fbs;
    const float* fln_g; const float* fln_b;
    const float* opW; const float* opb;
    float* xg0; float* xg1;      // ping-pong x buffers (131072 each): x0,x2 -> xg0; x1,x3 -> xg1
    float* h0;  float* q0;       // even-layer h/q
    float* h1;  float* q1;       // odd-layer h/q
    float* pmin; float* poff; float* pdiag;  // layers 0..2 partials, 3*4096 each
    int* bar;                    // [0..7] ticket counters, [8] ready flag
    float* out;                  // 64
};

// Lightweight device-scope grid barrier. Each call site uses a unique ticket
// counter (never reset). Counters live in poisoned ws; block 0 zeroes them and
// publishes MAGIC; everyone gates on MAGIC at barrier 0 (program order makes
// later barriers safe). Agent-scope atomics put the coherence point at the LLC
// (per-XCD L2s are not coherent).
__device__ __forceinline__ void gbar(int* bar, int idx, bool wait) {
    __syncthreads();
    if (threadIdx.x == 0) {
        if (idx == 0) {
            while (__hip_atomic_load(&bar[8], __ATOMIC_RELAXED,
                                     __HIP_MEMORY_SCOPE_AGENT) != MAGIC) {
                __builtin_amdgcn_s_sleep(1);
            }
        }
        __threadfence();  // release: write back dirty L2 so other XCDs see our stores
        __hip_atomic_fetch_add(&bar[idx], 1, __ATOMIC_ACQ_REL,
                               __HIP_MEMORY_SCOPE_AGENT);
        if (wait) {
            while (__hip_atomic_load(&bar[idx], __ATOMIC_RELAXED,
                                     __HIP_MEMORY_SCOPE_AGENT) < NBLK) {
                __builtin_amdgcn_s_sleep(1);
            }
            __threadfence();  // acquire: invalidate local caches
        }
    }
    __syncthreads();
}

// Grid: 256 blocks x 512 threads = one thread per (row, channel).
// A row (b,xi,y) is exactly one wave (64 lanes = 64 channels).
__launch_bounds__(512, 1)
__global__ void fused_all(Params p) {
    const int tid  = threadIdx.x;
    const int blk  = blockIdx.x;
    const int gtid = blk * 512 + tid;

    const int row = gtid >> 6;            // (b*32+xi)*32 + y
    const int c   = gtid & 63;            // head*16 + d
    const int d   = c & 15;
    const int rl  = tid >> 6;             // row-in-block 0..7
    const int y   = row & 31;
    const int xi  = (row >> 5) & 31;
    const int b   = row >> 10;

    const int r0      = blk * 8;
    const int b_blk   = r0 >> 10;
    const int xi_blk  = (r0 >> 5) & 31;
    const int slab_off = (b_blk * 1024 + xi_blk * 32) * 64;  // 2048 floats

    __shared__ float qx_s[2048];          // q slab (b_blk, xi_blk, a=0..31)
    __shared__ float hx_s[2048];
    __shared__ float xrow[8][64];         // current x for our 8 rows
    __shared__ float xu_s[8][64];
    __shared__ float adj8[8];
    // epilogue scratch (block 0)
    __shared__ float sm_mn[512], sm_off[512], sm_dg[512];
    __shared__ float rmx[128], rmn[128];
    __shared__ float pooled_s[256];
    __shared__ float scores_s[64];

    // ---- init barrier state (block 0) ----
    if (blk == 0 && tid == 0) {
        for (int i = 0; i < 8; ++i)
            __hip_atomic_store(&p.bar[i], 0, __ATOMIC_RELAXED, __HIP_MEMORY_SCOPE_AGENT);
        __threadfence();
        __hip_atomic_store(&p.bar[8], MAGIC, __ATOMIC_RELEASE, __HIP_MEMORY_SCOPE_AGENT);
    }

    // ---- per-block adjacency for OUR 8 rows (redundant scan, no grid sync) ----
    if (tid < 8) adj8[tid] = 0.0f;
    __syncthreads();
    for (int e2 = tid; e2 < p.E; e2 += 512) {
        int e0 = p.ei[e2], e1 = p.ei[p.E + e2];
        int g  = p.batch[e0];
        int tr = (g * 32 + (e0 - g * 32)) * 32 + (e1 - g * 32);
        int lo = tr - r0;
        if ((unsigned)lo < 8u) atomicAdd(&adj8[lo], 1.0f);
    }
    __syncthreads();
    const float adjv = (xi == y) ? 2.0f : adj8[rl];

    for (int layer = 0; layer < 4; ++layer) {
        const float* W     = layer == 0 ? p.W0  : p.Ws  + (layer - 1) * 4096;
        const float* bw    = layer == 0 ? p.b0  : p.bs  + (layer - 1) * 64;
        const float* fW    = layer == 0 ? p.fW0 : p.fWs + (layer - 1) * 8192;
        const float* fb    = layer == 0 ? p.fb0 : p.fbs + (layer - 1) * 64;
        const float* lg    = p.ln_g  + layer * 16;
        const float* lb    = p.ln_b  + layer * 16;
        const float* fg    = p.fln_g + layer * 64;
        const float* fbeta = p.fln_b + layer * 64;
        float* hbuf = (layer & 1) ? p.h1 : p.h0;
        float* qbuf = (layer & 1) ? p.q1 : p.q0;
        float* xout = (layer & 1) ? p.xg1 : p.xg0;

        // ---- Phase L: h = x@W.T + b ; q = LN16(h). Row-local (wave-local). ----
        float acc;
        if (layer == 0) {
            acc = fmaf(W[c], adjv, bw[c]);
        } else {
            acc = bw[c];
            const float* Wr = W + c * 64;
            #pragma unroll
            for (int j = 0; j < 64; ++j) acc = fmaf(Wr[j], xrow[rl][j], acc);
        }
        hbuf[gtid] = acc;
        float s1 = acc;
        #pragma unroll
        for (int m = 1; m < 16; m <<= 1) s1 += __shfl_xor(s1, m, 16);
        float mean = s1 * 0.0625f;
        float dv = acc - mean;
        float s2 = dv * dv;
        #pragma unroll
        for (int m = 1; m < 16; m <<= 1) s2 += __shfl_xor(s2, m, 16);
        qbuf[gtid] = dv * rsqrtf(s2 * 0.0625f + EPS) * lg[d] + lb[d];

        gbar(p.bar, layer, true);   // the ONE barrier per layer

        // ---- pool partials for previous layer's x (blocks 0..7) ----
        if (layer > 0 && gtid < 4096) {
            const float* xprev = ((layer - 1) & 1) ? p.xg1 : p.xg0;
            int bn = gtid >> 6, e = gtid & 63;
            int nn = bn & 31;
            const float* xp = xprev + bn * 2048 + e;
            float mn = 1e30f, off = -1e30f, dg = 0.0f;
            #pragma unroll
            for (int m2 = 0; m2 < 32; ++m2) {
                float v = xp[m2 * 64];
                mn = fminf(mn, v);
                if (m2 == nn) dg = v; else off = fmaxf(off, v);
            }
            int o = (layer - 1) * 4096 + gtid;
            p.pmin[o] = mn; p.poff[o] = off; p.pdiag[o] = dg;
        }

        // ---- Phase A: attention (two-pass, register arrays) ----
        ((float4*)qx_s)[tid] = ((const float4*)(qbuf + slab_off))[tid];
        ((float4*)hx_s)[tid] = ((const float4*)(hbuf + slab_off))[tid];
        __syncthreads();

        const float gl = lg[d], bl = lb[d];
        const float* qy = qbuf + (b * 1024 + y) * 64 + c;   // + a*2048
        const float* hy = hbuf + (b * 1024 + y) * 64 + c;
        float sarr[32], narr[32];
        #pragma unroll
        for (int a = 0; a < 32; ++a) {
            float qxv = qx_s[a * 64 + c];
            float hxv = hx_s[a * 64 + c];
            float qyv = qy[a * 2048];
            float hyv = hy[a * 2048];
            float rdot = qxv * qyv;
            float pp   = hxv * hyv;
            float rsum = pp;
            float rsq  = pp * pp;
            #pragma unroll
            for (int m = 1; m < 16; m <<= 1) {
                rdot += __shfl_xor(rdot, m, 16);
                rsum += __shfl_xor(rsum, m, 16);
                rsq  += __shfl_xor(rsq,  m, 16);
            }
            sarr[a] = rdot * 0.25f;                  // / sqrt(HD)
            float pmean = rsum * 0.0625f;
            float pvar  = fmaxf(rsq * 0.0625f - pmean * pmean, 0.0f);
            narr[a] = (pp - pmean) * rsqrtf(pvar + EPS) * gl;
        }
        float mx = sarr[0];
        #pragma unroll
        for (int a = 1; a < 32; ++a) mx = fmaxf(mx, sarr[a]);
        float lsum = 0.0f, asum = 0.0f;
        #pragma unroll
        for (int a = 0; a < 32; ++a) {
            float ee = __expf(sarr[a] - mx);
            lsum += ee;
            asum = fmaf(ee, narr[a], asum);
        }
        xu_s[rl][c] = asum / lsum + bl;   // softmax weights sum to 1 -> +lb once

        // ---- fin: y = concat([x, xu]) @ fW.T + fb, LN64. Wave-local. ----
        const int K = (layer == 0) ? 65 : 128;
        const float* Wr2 = fW + c * K;
        float acc2 = fb[c];
        if (layer == 0) {
            acc2 = fmaf(Wr2[0], adjv, acc2);
            #pragma unroll
            for (int j = 0; j < 64; ++j) acc2 = fmaf(Wr2[1 + j], xu_s[rl][j], acc2);
        } else {
            #pragma unroll
            for (int j = 0; j < 64; ++j) acc2 = fmaf(Wr2[j], xrow[rl][j], acc2);
            #pragma unroll
            for (int j = 0; j < 64; ++j) acc2 = fmaf(Wr2[64 + j], xu_s[rl][j], acc2);
        }
        float t1 = acc2;
        #pragma unroll
        for (int m = 1; m < 64; m <<= 1) t1 += __shfl_xor(t1, m, 64);
        float mu = t1 * (1.0f / 64.0f);
        float dv2 = acc2 - mu;
        float t2 = dv2 * dv2;
        #pragma unroll
        for (int m = 1; m < 64; m <<= 1) t2 += __shfl_xor(t2, m, 64);
        float xnew = dv2 * rsqrtf(t2 * (1.0f / 64.0f) + EPS) * fg[c] + fbeta[c];
        xrow[rl][c] = xnew;       // wave-local handoff to next Phase L
        xout[gtid]  = xnew;       // global copy for pool-partial readers
    }

    // ---- final barrier: non-zero blocks arrive and exit ----
    gbar(p.bar, 4, blk == 0);
    if (blk != 0) return;

    // ================= epilogue (block 0 only) =================
    // layer-3 pool partials directly from x3 (= xg1)
    {
        int k = tid >> 6, e = tid & 63;
        float mn8 = 1e30f, off8 = -1e30f, dg8 = -1e30f;
        for (int it = 0; it < 8; ++it) {
            int bn = k * 8 + it;          // 8 consecutive n of one graph
            int nn = bn & 31;
            const float* xp = p.xg1 + bn * 2048 + e;
            float mn = 1e30f, off = -1e30f, dg = 0.0f;
            #pragma unroll
            for (int m2 = 0; m2 < 32; ++m2) {
                float v = xp[m2 * 64];
                mn = fminf(mn, v);
                if (m2 == nn) dg = v; else off = fmaxf(off, v);
            }
            mn8 = fminf(mn8, mn); off8 = fmaxf(off8, off); dg8 = fmaxf(dg8, dg);
        }
        sm_mn[tid] = mn8; sm_off[tid] = off8; sm_dg[tid] = dg8;
        if (tid < 64) scores_s[tid] = 0.0f;
        __syncthreads();
    }

    for (int l = 0; l < 4; ++l) {
        float mn = 1e30f, off = -1e30f, dg = -1e30f;
        if (tid < 128) {
            int bb = tid >> 6, ee = tid & 63;
            if (l < 3) {
                for (int nn = 0; nn < 32; ++nn) {
                    int idx = l * 4096 + (bb * 32 + nn) * 64 + ee;
                    mn  = fminf(mn,  p.pmin[idx]);
                    off = fmaxf(off, p.poff[idx]);
                    dg  = fmaxf(dg,  p.pdiag[idx]);
                }
            } else {
                for (int j = 0; j < 4; ++j) {
                    int idx = (bb * 4 + j) * 64 + ee;
                    mn  = fminf(mn,  sm_mn[idx]);
                    off = fmaxf(off, sm_off[idx]);
                    dg  = fmaxf(dg,  sm_dg[idx]);
                }
            }
            rmx[tid] = dg; rmn[tid] = mn;
        }
        __syncthreads();
        if (tid == 0) {
            float gmx = -1e30f, gmn = 1e30f;
            for (int i2 = 0; i2 < 128; ++i2) {
                gmx = fmaxf(gmx, rmx[i2]);
                gmn = fminf(gmn, rmn[i2]);
            }
            rmx[0] = fabsf(gmx - gmn);   // |max_diag_global + max(-x)|
        }
        __syncthreads();
        float val = rmx[0];
        if (tid < 128) {
            int bb = tid >> 6, ee = tid & 63;
            pooled_s[bb * 128 + ee]      = dg;
            pooled_s[bb * 128 + 64 + ee] = fmaxf(off, dg - val);
        }
        __syncthreads();
        if (tid < 64) {
            int bb = tid >> 5, cc = tid & 31;
            const float* Wr = p.opW + l * 4096 + cc * 128;
            float a2 = p.opb[l * 32 + cc];
            for (int j = 0; j < 128; ++j) a2 = fmaf(Wr[j], pooled_s[bb * 128 + j], a2);
            scores_s[tid] += a2;
        }
        __syncthreads();
    }

    if (tid < 32) {
        float sA = scores_s[tid], sB = scores_s[32 + tid];
        float mu = 0.5f * (sA + sB);
        float va = 0.5f * ((sA - mu) * (sA - mu) + (sB - mu) * (sB - mu));
        float inv = rsqrtf(va + EPS);
        p.out[tid]      = (sA - mu) * inv;
        p.out[32 + tid] = (sB - mu) * inv;
    }
}

extern "C" void kernel_launch(void* const* d_in, const int* in_sizes, int n_in,
                              void* d_out, int out_size, void* d_ws, size_t ws_size,
                              hipStream_t stream) {
    Params prm;
    prm.ei    = (const int*)d_in[0];
    prm.batch = (const int*)d_in[1];
    prm.E     = in_sizes[0] / 2;
    prm.W0    = (const float*)d_in[2];
    prm.b0    = (const float*)d_in[3];
    prm.Ws    = (const float*)d_in[4];
    prm.bs    = (const float*)d_in[5];
    prm.ln_g  = (const float*)d_in[6];
    prm.ln_b  = (const float*)d_in[7];
    prm.fW0   = (const float*)d_in[8];
    prm.fb0   = (const float*)d_in[9];
    prm.fWs   = (const float*)d_in[10];
    prm.fbs   = (const float*)d_in[11];
    prm.fln_g = (const float*)d_in[12];
    prm.fln_b = (const float*)d_in[13];
    prm.opW   = (const float*)d_in[14];
    prm.opb   = (const float*)d_in[15];

    float* ws  = (float*)d_ws;
    prm.xg0   = ws;                   // 131072
    prm.xg1   = prm.xg0  + 131072;
    prm.h0    = prm.xg1  + 131072;
    prm.q0    = prm.h0   + 131072;
    prm.h1    = prm.q0   + 131072;
    prm.q1    = prm.h1   + 131072;
    prm.pmin  = prm.q1   + 131072;    // 3*4096
    prm.poff  = prm.pmin + 12288;
    prm.pdiag = prm.poff + 12288;
    prm.bar   = (int*)(prm.pdiag + 12288);  // 16 ints
    prm.out   = (float*)d_out;

    void* args[] = { &prm };
    hipLaunchCooperativeKernel((void*)fused_all, dim3(256), dim3(512), args, 0, stream);
}

// Round 5
// 285.955 us; speedup vs baseline: 1.6955x; 1.0671x over previous
//
#include <hip/hip_runtime.h>
#include <math.h>

// Shapes fixed by the reference: B=2, N=32, L=4, ED=64, H=4, HD=16
#define EPS 1e-5f
#define NBLK 256
#define MAGIC 0x13579BDF

struct Params {
    const int* ei; const int* batch; int E;
    const float* W0; const float* b0; const float* Ws; const float* bs;
    const float* ln_g; const float* ln_b;
    const float* fW0; const float* fb0; const float* fWs; const float* fbs;
    const float* fln_g; const float* fln_b;
    const float* opW; const float* opb;
    float* xg0; float* xg1;      // ping-pong x buffers: x0,x2 -> xg0; x1,x3 -> xg1
    float* h0;  float* q0;       // layer-2 h/q
    float* h1;  float* q1;       // layer-1/3 h/q
    float* pmin; float* poff; float* pdiag;  // layers 0..2 partials, 3*4096 each
    int* bar;                    // tree-barrier state (see layout in gbar)
    float* out;                  // 64
};

// Tree grid barrier, device scope. Layout (ints, all monotonic, never reset):
//   bar[site*256 + g*16]  : group counter (site<4, g<16), padded to 64B lines
//   bar[1024 + site*16]   : root counter
//   bar[1088 + site*16]   : release word (written once; spinners poll read-only)
//   bar[1152]             : ready flag (MAGIC after block 0 zeroes the above)
__device__ __forceinline__ void gbar(int* bar, int site, bool wait) {
    __syncthreads();
    if (threadIdx.x == 0) {
        if (site == 0) {   // gate first-ever use on block 0's init
            while (__hip_atomic_load(&bar[1152], __ATOMIC_RELAXED,
                                     __HIP_MEMORY_SCOPE_AGENT) != MAGIC)
                __builtin_amdgcn_s_sleep(1);
            __threadfence();   // acquire the zeroed counters
        }
        __threadfence();       // release: write back our XCD-L2 dirty data
        int g = blockIdx.x & 15;
        int r = __hip_atomic_fetch_add(&bar[site * 256 + g * 16], 1,
                                       __ATOMIC_ACQ_REL, __HIP_MEMORY_SCOPE_AGENT);
        if (r == 15) {         // last of my 16-block group
            int r2 = __hip_atomic_fetch_add(&bar[1024 + site * 16], 1,
                                            __ATOMIC_ACQ_REL, __HIP_MEMORY_SCOPE_AGENT);
            if (r2 == 15) {    // last group overall -> publish release word
                __hip_atomic_store(&bar[1088 + site * 16], 1,
                                   __ATOMIC_RELEASE, __HIP_MEMORY_SCOPE_AGENT);
            }
        }
        if (wait) {
            while (__hip_atomic_load(&bar[1088 + site * 16], __ATOMIC_RELAXED,
                                     __HIP_MEMORY_SCOPE_AGENT) == 0)
                __builtin_amdgcn_s_sleep(1);
            __threadfence();   // acquire: invalidate local caches
        }
    }
    __syncthreads();
}

// Grid: 256 blocks x 512 threads = one thread per (row, channel).
// A row (b,xi,y) is exactly one wave (64 lanes = 64 channels).
__launch_bounds__(512, 1)
__global__ void fused_all(Params p) {
    const int tid  = threadIdx.x;
    const int blk  = blockIdx.x;
    const int gtid = blk * 512 + tid;

    const int row = gtid >> 6;            // (b*32+xi)*32 + y
    const int c   = gtid & 63;            // head*16 + d
    const int d   = c & 15;
    const int rl  = tid >> 6;             // row-in-block 0..7
    const int y   = row & 31;
    const int b   = row >> 10;

    const int r0      = blk * 8;
    const int b_blk   = r0 >> 10;
    const int xi_blk  = (r0 >> 5) & 31;
    const int y0      = r0 & 31;          // 0,8,16,24
    const int slab_off = (b_blk * 1024 + xi_blk * 32) * 64;  // 2048 floats

    __shared__ float qx_s[2048];          // q slab (b_blk, xi_blk, a=0..31)
    __shared__ float hx_s[2048];
    __shared__ float xrow[8][64];         // current x for our 8 rows
    __shared__ float xu_s[8][64];
    __shared__ float xslab[32];           // layer-0: adj[b_blk, xi_blk, a]
    __shared__ float yslab[256];          // layer-0: adj[b_blk, a, y0+j] at [a*8+j]
    // epilogue scratch (block 0)
    __shared__ float sm_mn[512], sm_off[512], sm_dg[512];
    __shared__ float rmx[128], rmn[128];
    __shared__ float pooled_s[256];
    __shared__ float scores_s[64];

    // ---- init barrier state (block 0, cooperative) ----
    if (blk == 0) {
        for (int i = tid; i < 1152; i += 512)
            __hip_atomic_store(&p.bar[i], 0, __ATOMIC_RELAXED, __HIP_MEMORY_SCOPE_AGENT);
        __syncthreads();
        if (tid == 0) {
            __threadfence();
            __hip_atomic_store(&p.bar[1152], MAGIC, __ATOMIC_RELEASE, __HIP_MEMORY_SCOPE_AGENT);
        }
    }

    // ---- layer-0 adjacency slabs: block-local redundant edge scan ----
    if (tid < 32)  xslab[tid] = 0.0f;
    if (tid < 256) yslab[tid] = 0.0f;
    __syncthreads();
    for (int e2 = tid; e2 < p.E; e2 += 512) {
        int e0 = p.ei[e2], e1 = p.ei[p.E + e2];
        int g  = p.batch[e0];
        if (g == b_blk) {
            int ls = e0 - g * 32, ld = e1 - g * 32;
            if (ls == xi_blk) atomicAdd(&xslab[ld], 1.0f);
            unsigned dy = (unsigned)(ld - y0);
            if (dy < 8u) atomicAdd(&yslab[ls * 8 + dy], 1.0f);
        }
    }
    __syncthreads();
    if (tid == 0) xslab[xi_blk] = 2.0f;
    if (tid < 8)  yslab[(y0 + tid) * 8 + tid] = 2.0f;   // diag a==y
    __syncthreads();

    // ======================= LAYER 0 (no grid barrier) =======================
    {
        const float* lg    = p.ln_g;
        const float* lb    = p.ln_b;
        const float* fg    = p.fln_g;
        const float* fbeta = p.fln_b;
        const float gl = lg[d], bl = lb[d];

        // closed-form LN16 of the rank-1 h = W*v + b : per-head stats
        float Wc = p.W0[c], bc = p.b0[c];
        float sW = Wc, sB = bc;
        #pragma unroll
        for (int m = 1; m < 16; m <<= 1) {
            sW += __shfl_xor(sW, m, 16);
            sB += __shfl_xor(sB, m, 16);
        }
        float Ac = Wc - sW * 0.0625f;
        float Bc = bc - sB * 0.0625f;
        float sAA = Ac * Ac, sAB = Ac * Bc, sBB = Bc * Bc;
        #pragma unroll
        for (int m = 1; m < 16; m <<= 1) {
            sAA += __shfl_xor(sAA, m, 16);
            sAB += __shfl_xor(sAB, m, 16);
            sBB += __shfl_xor(sBB, m, 16);
        }
        const float varW = sAA * 0.0625f, covWB = sAB * 0.0625f, varB = sBB * 0.0625f;

        const float adjv = xslab[y];   // own row's adjacency value (diag folded in)

        // attention with on-the-fly h/q from adj slabs
        float sarr[32], narr[32];
        #pragma unroll
        for (int a = 0; a < 32; ++a) {
            float vx = xslab[a];
            float vy = yslab[a * 8 + rl];
            float hx = fmaf(Wc, vx, bc);
            float hy = fmaf(Wc, vy, bc);
            float qx = fmaf(Ac, vx, Bc) *
                       rsqrtf(fmaf(fmaf(varW, vx, 2.0f * covWB), vx, varB) + EPS) * gl + bl;
            float qy = fmaf(Ac, vy, Bc) *
                       rsqrtf(fmaf(fmaf(varW, vy, 2.0f * covWB), vy, varB) + EPS) * gl + bl;
            float rdot = qx * qy;
            float pp   = hx * hy;
            float rsum = pp, rsq = pp * pp;
            #pragma unroll
            for (int m = 1; m < 16; m <<= 1) {
                rdot += __shfl_xor(rdot, m, 16);
                rsum += __shfl_xor(rsum, m, 16);
                rsq  += __shfl_xor(rsq,  m, 16);
            }
            sarr[a] = rdot * 0.25f;
            float pmean = rsum * 0.0625f;
            float pvar  = fmaxf(rsq * 0.0625f - pmean * pmean, 0.0f);
            narr[a] = (pp - pmean) * rsqrtf(pvar + EPS) * gl;
        }
        float mx = sarr[0];
        #pragma unroll
        for (int a = 1; a < 32; ++a) mx = fmaxf(mx, sarr[a]);
        float lsum = 0.0f, asum = 0.0f;
        #pragma unroll
        for (int a = 0; a < 32; ++a) {
            float ee = __expf(sarr[a] - mx);
            lsum += ee;
            asum = fmaf(ee, narr[a], asum);
        }
        xu_s[rl][c] = asum / lsum + bl;
        __syncthreads();

        // fin (K=65) + LN64
        const float* Wr2 = p.fW0 + c * 65;
        float acc2 = fmaf(Wr2[0], adjv, p.fb0[c]);
        #pragma unroll
        for (int j = 0; j < 64; ++j) acc2 = fmaf(Wr2[1 + j], xu_s[rl][j], acc2);
        float t1 = acc2;
        #pragma unroll
        for (int m = 1; m < 64; m <<= 1) t1 += __shfl_xor(t1, m, 64);
        float mu = t1 * (1.0f / 64.0f);
        float dv2 = acc2 - mu;
        float t2 = dv2 * dv2;
        #pragma unroll
        for (int m = 1; m < 64; m <<= 1) t2 += __shfl_xor(t2, m, 64);
        float xnew = dv2 * rsqrtf(t2 * (1.0f / 64.0f) + EPS) * fg[c] + fbeta[c];
        xrow[rl][c] = xnew;
        p.xg0[gtid] = xnew;
    }

    // ======================= LAYERS 1..3 =======================
    for (int layer = 1; layer < 4; ++layer) {
        const float* W     = p.Ws  + (layer - 1) * 4096;
        const float* bw    = p.bs  + (layer - 1) * 64;
        const float* fW    = p.fWs + (layer - 1) * 8192;
        const float* fb    = p.fbs + (layer - 1) * 64;
        const float* lg    = p.ln_g  + layer * 16;
        const float* lb    = p.ln_b  + layer * 16;
        const float* fg    = p.fln_g + layer * 64;
        const float* fbeta = p.fln_b + layer * 64;
        float* hbuf = (layer & 1) ? p.h1 : p.h0;
        float* qbuf = (layer & 1) ? p.q1 : p.q0;
        float* xout = (layer & 1) ? p.xg1 : p.xg0;

        // ---- Phase L: h = x@W.T + b ; q = LN16(h). Wave-local. ----
        float acc = bw[c];
        {
            const float* Wr = W + c * 64;
            #pragma unroll
            for (int j = 0; j < 64; ++j) acc = fmaf(Wr[j], xrow[rl][j], acc);
        }
        hbuf[gtid] = acc;
        float s1 = acc;
        #pragma unroll
        for (int m = 1; m < 16; m <<= 1) s1 += __shfl_xor(s1, m, 16);
        float mean = s1 * 0.0625f;
        float dv = acc - mean;
        float s2 = dv * dv;
        #pragma unroll
        for (int m = 1; m < 16; m <<= 1) s2 += __shfl_xor(s2, m, 16);
        qbuf[gtid] = dv * rsqrtf(s2 * 0.0625f + EPS) * lg[d] + lb[d];

        gbar(p.bar, layer - 1, true);   // the ONE barrier per layer

        // ---- pool partials for previous layer's x (blocks 0..7) ----
        if (gtid < 4096) {
            const float* xprev = ((layer - 1) & 1) ? p.xg1 : p.xg0;
            int bn = gtid >> 6, e = gtid & 63;
            int nn = bn & 31;
            const float* xp = xprev + bn * 2048 + e;
            float mn = 1e30f, off = -1e30f, dg = 0.0f;
            #pragma unroll
            for (int m2 = 0; m2 < 32; ++m2) {
                float v = xp[m2 * 64];
                mn = fminf(mn, v);
                if (m2 == nn) dg = v; else off = fmaxf(off, v);
            }
            int o = (layer - 1) * 4096 + gtid;
            p.pmin[o] = mn; p.poff[o] = off; p.pdiag[o] = dg;
        }

        // ---- Phase A: attention. Batch all y-slab loads first. ----
        float4 qslab4 = ((const float4*)(qbuf + slab_off))[tid];
        float4 hslab4 = ((const float4*)(hbuf + slab_off))[tid];
        const float* qy = qbuf + (b * 1024 + y) * 64 + c;   // + a*2048
        const float* hy = hbuf + (b * 1024 + y) * 64 + c;
        float qyv[32], hyv[32];
        #pragma unroll
        for (int a = 0; a < 32; ++a) {
            qyv[a] = qy[a * 2048];
            hyv[a] = hy[a * 2048];
        }
        ((float4*)qx_s)[tid] = qslab4;
        ((float4*)hx_s)[tid] = hslab4;
        __syncthreads();

        const float gl = lg[d], bl = lb[d];
        float sarr[32], narr[32];
        #pragma unroll
        for (int a = 0; a < 32; ++a) {
            float qxv = qx_s[a * 64 + c];
            float hxv = hx_s[a * 64 + c];
            float rdot = qxv * qyv[a];
            float pp   = hxv * hyv[a];
            float rsum = pp, rsq = pp * pp;
            #pragma unroll
            for (int m = 1; m < 16; m <<= 1) {
                rdot += __shfl_xor(rdot, m, 16);
                rsum += __shfl_xor(rsum, m, 16);
                rsq  += __shfl_xor(rsq,  m, 16);
            }
            sarr[a] = rdot * 0.25f;
            float pmean = rsum * 0.0625f;
            float pvar  = fmaxf(rsq * 0.0625f - pmean * pmean, 0.0f);
            narr[a] = (pp - pmean) * rsqrtf(pvar + EPS) * gl;
        }
        float mx = sarr[0];
        #pragma unroll
        for (int a = 1; a < 32; ++a) mx = fmaxf(mx, sarr[a]);
        float lsum = 0.0f, asum = 0.0f;
        #pragma unroll
        for (int a = 0; a < 32; ++a) {
            float ee = __expf(sarr[a] - mx);
            lsum += ee;
            asum = fmaf(ee, narr[a], asum);
        }
        xu_s[rl][c] = asum / lsum + bl;
        __syncthreads();

        // ---- fin: y = concat([x, xu]) @ fW.T + fb, LN64. Wave-local. ----
        const float* Wr2 = fW + c * 128;
        float acc2 = fb[c];
        #pragma unroll
        for (int j = 0; j < 64; ++j) acc2 = fmaf(Wr2[j], xrow[rl][j], acc2);
        #pragma unroll
        for (int j = 0; j < 64; ++j) acc2 = fmaf(Wr2[64 + j], xu_s[rl][j], acc2);
        float t1 = acc2;
        #pragma unroll
        for (int m = 1; m < 64; m <<= 1) t1 += __shfl_xor(t1, m, 64);
        float mu = t1 * (1.0f / 64.0f);
        float dv2 = acc2 - mu;
        float t2 = dv2 * dv2;
        #pragma unroll
        for (int m = 1; m < 64; m <<= 1) t2 += __shfl_xor(t2, m, 64);
        float xnew = dv2 * rsqrtf(t2 * (1.0f / 64.0f) + EPS) * fg[c] + fbeta[c];
        __syncthreads();          // xu_s reuse hazard across layers
        xrow[rl][c] = xnew;
        xout[gtid]  = xnew;
    }

    // ---- final barrier: non-zero blocks arrive and exit ----
    gbar(p.bar, 3, blk == 0);
    if (blk != 0) return;

    // ================= epilogue (block 0 only) =================
    // layer-3 pool partials directly from x3 (= xg1)
    {
        int k = tid >> 6, e = tid & 63;
        float mn8 = 1e30f, off8 = -1e30f, dg8 = -1e30f;
        for (int it = 0; it < 8; ++it) {
            int bn = k * 8 + it;
            int nn = bn & 31;
            const float* xp = p.xg1 + bn * 2048 + e;
            float mn = 1e30f, off = -1e30f, dg = 0.0f;
            #pragma unroll
            for (int m2 = 0; m2 < 32; ++m2) {
                float v = xp[m2 * 64];
                mn = fminf(mn, v);
                if (m2 == nn) dg = v; else off = fmaxf(off, v);
            }
            mn8 = fminf(mn8, mn); off8 = fmaxf(off8, off); dg8 = fmaxf(dg8, dg);
        }
        sm_mn[tid] = mn8; sm_off[tid] = off8; sm_dg[tid] = dg8;
        if (tid < 64) scores_s[tid] = 0.0f;
        __syncthreads();
    }

    for (int l = 0; l < 4; ++l) {
        float mn = 1e30f, off = -1e30f, dg = -1e30f;
        if (tid < 128) {
            int bb = tid >> 6, ee = tid & 63;
            if (l < 3) {
                for (int nn = 0; nn < 32; ++nn) {
                    int idx = l * 4096 + (bb * 32 + nn) * 64 + ee;
                    mn  = fminf(mn,  p.pmin[idx]);
                    off = fmaxf(off, p.poff[idx]);
                    dg  = fmaxf(dg,  p.pdiag[idx]);
                }
            } else {
                for (int j = 0; j < 4; ++j) {
                    int idx = (bb * 4 + j) * 64 + ee;
                    mn  = fminf(mn,  sm_mn[idx]);
                    off = fmaxf(off, sm_off[idx]);
                    dg  = fmaxf(dg,  sm_dg[idx]);
                }
            }
            rmx[tid] = dg; rmn[tid] = mn;
        }
        __syncthreads();
        if (tid == 0) {
            float gmx = -1e30f, gmn = 1e30f;
            for (int i2 = 0; i2 < 128; ++i2) {
                gmx = fmaxf(gmx, rmx[i2]);
                gmn = fminf(gmn, rmn[i2]);
            }
            rmx[0] = fabsf(gmx - gmn);   // |max_diag_global + max(-x)|
        }
        __syncthreads();
        float val = rmx[0];
        if (tid < 128) {
            int bb = tid >> 6, ee = tid & 63;
            pooled_s[bb * 128 + ee]      = dg;
            pooled_s[bb * 128 + 64 + ee] = fmaxf(off, dg - val);
        }
        __syncthreads();
        if (tid < 64) {
            int bb = tid >> 5, cc = tid & 31;
            const float* Wr = p.opW + l * 4096 + cc * 128;
            float a2 = p.opb[l * 32 + cc];
            for (int j = 0; j < 128; ++j) a2 = fmaf(Wr[j], pooled_s[bb * 128 + j], a2);
            scores_s[tid] += a2;
        }
        __syncthreads();
    }

    if (tid < 32) {
        float sA = scores_s[tid], sB = scores_s[32 + tid];
        float mu = 0.5f * (sA + sB);
        float va = 0.5f * ((sA - mu) * (sA - mu) + (sB - mu) * (sB - mu));
        float inv = rsqrtf(va + EPS);
        p.out[tid]      = (sA - mu) * inv;
        p.out[32 + tid] = (sB - mu) * inv;
    }
}

extern "C" void kernel_launch(void* const* d_in, const int* in_sizes, int n_in,
                              void* d_out, int out_size, void* d_ws, size_t ws_size,
                              hipStream_t stream) {
    Params prm;
    prm.ei    = (const int*)d_in[0];
    prm.batch = (const int*)d_in[1];
    prm.E     = in_sizes[0] / 2;
    prm.W0    = (const float*)d_in[2];
    prm.b0    = (const float*)d_in[3];
    prm.Ws    = (const float*)d_in[4];
    prm.bs    = (const float*)d_in[5];
    prm.ln_g  = (const float*)d_in[6];
    prm.ln_b  = (const float*)d_in[7];
    prm.fW0   = (const float*)d_in[8];
    prm.fb0   = (const float*)d_in[9];
    prm.fWs   = (const float*)d_in[10];
    prm.fbs   = (const float*)d_in[11];
    prm.fln_g = (const float*)d_in[12];
    prm.fln_b = (const float*)d_in[13];
    prm.opW   = (const float*)d_in[14];
    prm.opb   = (const float*)d_in[15];

    float* ws  = (float*)d_ws;
    prm.xg0   = ws;                   // 131072
    prm.xg1   = prm.xg0  + 131072;
    prm.h0    = prm.xg1  + 131072;
    prm.q0    = prm.h0   + 131072;
    prm.h1    = prm.q0   + 131072;
    prm.q1    = prm.h1   + 131072;
    prm.pmin  = prm.q1   + 131072;    // 3*4096
    prm.poff  = prm.pmin + 12288;
    prm.pdiag = prm.poff + 12288;
    prm.bar   = (int*)(prm.pdiag + 12288);  // 1153 ints used
    prm.out   = (float*)d_out;

    void* args[] = { &prm };
    hipLaunchCooperativeKernel((void*)fused_all, dim3(256), dim3(512), args, 0, stream);
}

// Round 6
// 248.401 us; speedup vs baseline: 1.9519x; 1.1512x over previous
//
#include <hip/hip_runtime.h>
#include <math.h>

// Shapes fixed by the reference: B=2, N=32, L=4, ED=64, H=4, HD=16
#define EPS 1e-5f
#define MAGIC 0x13579BDF

struct Params {
    const int* ei; const int* batch; int E;
    const float* W0; const float* b0; const float* Ws; const float* bs;
    const float* ln_g; const float* ln_b;
    const float* fW0; const float* fb0; const float* fWs; const float* fbs;
    const float* fln_g; const float* fln_b;
    const float* opW; const float* opb;
    float* h0; float* q0;        // layer-2 h/q
    float* h1; float* q1;        // layer-1/3 h/q
    float* Pmin; float* Poff; float* Pdg;  // [4 layers][256 blocks][64 e]
    int* bar;                    // tree-barrier state
    float* out;                  // 64
};

// Tree grid barrier, device scope, MINIMAL cache maintenance:
// exactly one L2 writeback (RELEASE arrival add) and one L2 invalidate
// (ACQUIRE fence after release-word observed) per block per barrier.
// Layout (ints, monotonic, never reset):
//   bar[site*256 + g*16] : group counters (site<4, g<16), line-padded
//   bar[1024 + site*16]  : root counter
//   bar[1088 + site*16]  : release word
//   bar[1152]            : ready flag (MAGIC after block 0 zeroes the above)
__device__ __forceinline__ void gbar(int* bar, int site, bool wait) {
    __syncthreads();
    if (threadIdx.x == 0) {
        if (site == 0) {   // gate first use on block 0's init
            while (__hip_atomic_load(&bar[1152], __ATOMIC_RELAXED,
                                     __HIP_MEMORY_SCOPE_AGENT) != MAGIC)
                __builtin_amdgcn_s_sleep(1);
        }
        int g = blockIdx.x & 15;
        // RELEASE: one buffer_wbl2 (flush our XCD-L2 dirty data), then the add
        int r = __hip_atomic_fetch_add(&bar[site * 256 + g * 16], 1,
                                       __ATOMIC_RELEASE, __HIP_MEMORY_SCOPE_AGENT);
        if (r == 15) {
            int r2 = __hip_atomic_fetch_add(&bar[1024 + site * 16], 1,
                                            __ATOMIC_RELAXED, __HIP_MEMORY_SCOPE_AGENT);
            if (r2 == 15)
                __hip_atomic_store(&bar[1088 + site * 16], 1,
                                   __ATOMIC_RELAXED, __HIP_MEMORY_SCOPE_AGENT);
        }
        if (wait) {
            while (__hip_atomic_load(&bar[1088 + site * 16], __ATOMIC_RELAXED,
                                     __HIP_MEMORY_SCOPE_AGENT) == 0)
                __builtin_amdgcn_s_sleep(1);
            __builtin_amdgcn_fence(__ATOMIC_ACQUIRE, "agent");  // one buffer_inv
        }
    }
    __syncthreads();
}

// Grid: 256 blocks x 512 threads = one thread per (row, channel).
// A row (b,xi,y) is exactly one wave (64 lanes = 64 channels).
__launch_bounds__(512, 1)
__global__ void fused_all(Params p) {
    const int tid  = threadIdx.x;
    const int blk  = blockIdx.x;
    const int gtid = blk * 512 + tid;

    const int row = gtid >> 6;            // (b*32+xi)*32 + y
    const int c   = gtid & 63;            // head*16 + d
    const int d   = c & 15;
    const int rl  = tid >> 6;             // row-in-block 0..7
    const int y   = row & 31;
    const int b   = row >> 10;

    const int r0      = blk * 8;
    const int b_blk   = r0 >> 10;
    const int xi_blk  = (r0 >> 5) & 31;
    const int y0      = r0 & 31;          // 0,8,16,24
    const int rld     = xi_blk - y0;      // diag row-in-block if in [0,8)
    const int slab_off = (b_blk * 1024 + xi_blk * 32) * 64;

    __shared__ float qx_s[2048];          // q slab (b_blk, xi_blk, a=0..31)
    __shared__ float hx_s[2048];
    __shared__ float xrow[8][64];         // current x for our 8 rows
    __shared__ float xu_s[8][64];
    __shared__ float xslab[32];           // layer-0: adj[b_blk, xi_blk, a]
    __shared__ float yslab[256];          // layer-0: adj[b_blk, a, y0+j] at [a*8+j]
    // epilogue scratch (block 0)
    __shared__ float sm_mn[512], sm_off[512], sm_dg[512];
    __shared__ float psum[512];
    __shared__ float vals[4];
    __shared__ float scores_s[64];

    // ---- init barrier state (block 0) ----
    if (blk == 0) {
        for (int i = tid; i < 1152; i += 512)
            __hip_atomic_store(&p.bar[i], 0, __ATOMIC_RELAXED, __HIP_MEMORY_SCOPE_AGENT);
        __syncthreads();
        if (tid == 0)
            __hip_atomic_store(&p.bar[1152], MAGIC, __ATOMIC_RELEASE, __HIP_MEMORY_SCOPE_AGENT);
    }

    // ---- layer-0 adjacency slabs: block-local redundant edge scan ----
    if (tid < 32)  xslab[tid] = 0.0f;
    if (tid < 256) yslab[tid] = 0.0f;
    __syncthreads();
    for (int e2 = tid; e2 < p.E; e2 += 512) {
        int e0 = p.ei[e2], e1 = p.ei[p.E + e2];
        int g  = p.batch[e0];
        if (g == b_blk) {
            int ls = e0 - g * 32, ld = e1 - g * 32;
            if (ls == xi_blk) atomicAdd(&xslab[ld], 1.0f);
            unsigned dy = (unsigned)(ld - y0);
            if (dy < 8u) atomicAdd(&yslab[ls * 8 + dy], 1.0f);
        }
    }
    __syncthreads();
    if (tid == 0) xslab[xi_blk] = 2.0f;
    if (tid < 8)  yslab[(y0 + tid) * 8 + tid] = 2.0f;   // diag a==y
    __syncthreads();

    // ======================= LAYER 0 (no grid barrier) =======================
    {
        const float gl = p.ln_g[d], bl = p.ln_b[d];

        // closed-form LN16 of the rank-1 h = W*v + b : per-head stats
        float Wc = p.W0[c], bc = p.b0[c];
        float sW = Wc, sB = bc;
        #pragma unroll
        for (int m = 1; m < 16; m <<= 1) {
            sW += __shfl_xor(sW, m, 16);
            sB += __shfl_xor(sB, m, 16);
        }
        float Ac = Wc - sW * 0.0625f;
        float Bc = bc - sB * 0.0625f;
        float sAA = Ac * Ac, sAB = Ac * Bc, sBB = Bc * Bc;
        #pragma unroll
        for (int m = 1; m < 16; m <<= 1) {
            sAA += __shfl_xor(sAA, m, 16);
            sAB += __shfl_xor(sAB, m, 16);
            sBB += __shfl_xor(sBB, m, 16);
        }
        const float varW = sAA * 0.0625f, covWB = sAB * 0.0625f, varB = sBB * 0.0625f;
        const float adjv = xslab[y];

        float sarr[32], narr[32];
        #pragma unroll
        for (int a = 0; a < 32; ++a) {
            float vx = xslab[a];
            float vy = yslab[a * 8 + rl];
            float hx = fmaf(Wc, vx, bc);
            float hy = fmaf(Wc, vy, bc);
            float qx = fmaf(Ac, vx, Bc) *
                       rsqrtf(fmaf(fmaf(varW, vx, 2.0f * covWB), vx, varB) + EPS) * gl + bl;
            float qy = fmaf(Ac, vy, Bc) *
                       rsqrtf(fmaf(fmaf(varW, vy, 2.0f * covWB), vy, varB) + EPS) * gl + bl;
            float rdot = qx * qy;
            float pp   = hx * hy;
            float rsum = pp, rsq = pp * pp;
            #pragma unroll
            for (int m = 1; m < 16; m <<= 1) {
                rdot += __shfl_xor(rdot, m, 16);
                rsum += __shfl_xor(rsum, m, 16);
                rsq  += __shfl_xor(rsq,  m, 16);
            }
            sarr[a] = rdot * 0.25f;
            float pmean = rsum * 0.0625f;
            float pvar  = fmaxf(rsq * 0.0625f - pmean * pmean, 0.0f);
            narr[a] = (pp - pmean) * rsqrtf(pvar + EPS) * gl;
        }
        float mx = sarr[0];
        #pragma unroll
        for (int a = 1; a < 32; ++a) mx = fmaxf(mx, sarr[a]);
        float lsum = 0.0f, asum = 0.0f;
        #pragma unroll
        for (int a = 0; a < 32; ++a) {
            float ee = __expf(sarr[a] - mx);
            lsum += ee;
            asum = fmaf(ee, narr[a], asum);
        }
        xu_s[rl][c] = asum / lsum + bl;   // wave-local (no sync needed)

        // fin (K=65) + LN64
        const float* Wr2 = p.fW0 + c * 65;
        float acc2 = fmaf(Wr2[0], adjv, p.fb0[c]);
        #pragma unroll
        for (int j = 0; j < 64; ++j) acc2 = fmaf(Wr2[1 + j], xu_s[rl][j], acc2);
        float t1 = acc2;
        #pragma unroll
        for (int m = 1; m < 64; m <<= 1) t1 += __shfl_xor(t1, m, 64);
        float mu = t1 * (1.0f / 64.0f);
        float dv2 = acc2 - mu;
        float t2 = dv2 * dv2;
        #pragma unroll
        for (int m = 1; m < 64; m <<= 1) t2 += __shfl_xor(t2, m, 64);
        xrow[rl][c] = dv2 * rsqrtf(t2 * (1.0f / 64.0f) + EPS) * p.fln_g[c] + p.fln_b[c];
    }
    __syncthreads();
    // layer-0 pool partial over our 8 rows, straight from LDS
    if (tid < 64) {
        float mn = 1e30f, off = -1e30f, dg = -1e30f;
        #pragma unroll
        for (int r2 = 0; r2 < 8; ++r2) {
            float v = xrow[r2][tid];
            mn = fminf(mn, v);
            if (r2 == rld) dg = v; else off = fmaxf(off, v);
        }
        int o = blk * 64 + tid;
        p.Pmin[o] = mn; p.Poff[o] = off; p.Pdg[o] = dg;
    }

    // ======================= LAYERS 1..3 =======================
    for (int layer = 1; layer < 4; ++layer) {
        const float* W     = p.Ws  + (layer - 1) * 4096;
        const float* bw    = p.bs  + (layer - 1) * 64;
        const float* fW    = p.fWs + (layer - 1) * 8192;
        const float* fb    = p.fbs + (layer - 1) * 64;
        const float* lg    = p.ln_g  + layer * 16;
        const float* lb    = p.ln_b  + layer * 16;
        const float* fg    = p.fln_g + layer * 64;
        const float* fbeta = p.fln_b + layer * 64;
        float* hbuf = (layer & 1) ? p.h1 : p.h0;
        float* qbuf = (layer & 1) ? p.q1 : p.q0;

        // ---- Phase L: h = x@W.T + b ; q = LN16(h). Wave-local. ----
        float acc = bw[c];
        {
            const float* Wr = W + c * 64;
            #pragma unroll
            for (int j = 0; j < 64; ++j) acc = fmaf(Wr[j], xrow[rl][j], acc);
        }
        hbuf[gtid] = acc;
        float s1 = acc;
        #pragma unroll
        for (int m = 1; m < 16; m <<= 1) s1 += __shfl_xor(s1, m, 16);
        float mean = s1 * 0.0625f;
        float dv = acc - mean;
        float s2 = dv * dv;
        #pragma unroll
        for (int m = 1; m < 16; m <<= 1) s2 += __shfl_xor(s2, m, 16);
        qbuf[gtid] = dv * rsqrtf(s2 * 0.0625f + EPS) * lg[d] + lb[d];

        gbar(p.bar, layer - 1, true);   // the ONE barrier per layer

        // ---- Phase A: attention. Batch all y-slab loads first. ----
        float4 qslab4 = ((const float4*)(qbuf + slab_off))[tid];
        float4 hslab4 = ((const float4*)(hbuf + slab_off))[tid];
        const float* qy = qbuf + (b * 1024 + y) * 64 + c;   // + a*2048
        const float* hy = hbuf + (b * 1024 + y) * 64 + c;
        float qyv[32], hyv[32];
        #pragma unroll
        for (int a = 0; a < 32; ++a) {
            qyv[a] = qy[a * 2048];
            hyv[a] = hy[a * 2048];
        }
        ((float4*)qx_s)[tid] = qslab4;
        ((float4*)hx_s)[tid] = hslab4;
        __syncthreads();

        const float gl = lg[d], bl = lb[d];
        float sarr[32], narr[32];
        #pragma unroll
        for (int a = 0; a < 32; ++a) {
            float qxv = qx_s[a * 64 + c];
            float hxv = hx_s[a * 64 + c];
            float rdot = qxv * qyv[a];
            float pp   = hxv * hyv[a];
            float rsum = pp, rsq = pp * pp;
            #pragma unroll
            for (int m = 1; m < 16; m <<= 1) {
                rdot += __shfl_xor(rdot, m, 16);
                rsum += __shfl_xor(rsum, m, 16);
                rsq  += __shfl_xor(rsq,  m, 16);
            }
            sarr[a] = rdot * 0.25f;
            float pmean = rsum * 0.0625f;
            float pvar  = fmaxf(rsq * 0.0625f - pmean * pmean, 0.0f);
            narr[a] = (pp - pmean) * rsqrtf(pvar + EPS) * gl;
        }
        float mx = sarr[0];
        #pragma unroll
        for (int a = 1; a < 32; ++a) mx = fmaxf(mx, sarr[a]);
        float lsum = 0.0f, asum = 0.0f;
        #pragma unroll
        for (int a = 0; a < 32; ++a) {
            float ee = __expf(sarr[a] - mx);
            lsum += ee;
            asum = fmaf(ee, narr[a], asum);
        }
        xu_s[rl][c] = asum / lsum + bl;   // wave-local

        // ---- fin: y = concat([x, xu]) @ fW.T + fb, LN64. Wave-local. ----
        const float* Wr2 = fW + c * 128;
        float acc2 = fb[c];
        #pragma unroll
        for (int j = 0; j < 64; ++j) acc2 = fmaf(Wr2[j], xrow[rl][j], acc2);
        #pragma unroll
        for (int j = 0; j < 64; ++j) acc2 = fmaf(Wr2[64 + j], xu_s[rl][j], acc2);
        float t1 = acc2;
        #pragma unroll
        for (int m = 1; m < 64; m <<= 1) t1 += __shfl_xor(t1, m, 64);
        float mu = t1 * (1.0f / 64.0f);
        float dv2 = acc2 - mu;
        float t2 = dv2 * dv2;
        #pragma unroll
        for (int m = 1; m < 64; m <<= 1) t2 += __shfl_xor(t2, m, 64);
        float xnew = dv2 * rsqrtf(t2 * (1.0f / 64.0f) + EPS) * fg[c] + fbeta[c];
        xrow[rl][c] = xnew;            // wave-local write
        __syncthreads();               // publish xrow to wave 0 for pooling

        // pool partial for this layer, straight from LDS (uniform, all blocks)
        if (tid < 64) {
            float mn = 1e30f, off = -1e30f, dg = -1e30f;
            #pragma unroll
            for (int r2 = 0; r2 < 8; ++r2) {
                float v = xrow[r2][tid];
                mn = fminf(mn, v);
                if (r2 == rld) dg = v; else off = fmaxf(off, v);
            }
            int o = layer * 16384 + blk * 64 + tid;
            p.Pmin[o] = mn; p.Poff[o] = off; p.Pdg[o] = dg;
        }
    }

    // ---- final barrier: non-zero blocks arrive and exit ----
    gbar(p.bar, 3, blk == 0);
    if (blk != 0) return;

    // ================= epilogue (block 0 only) =================
    // stage 1: reduce 128 block-partials per (layer, graph, e) — coalesced
    {
        int l = tid >> 7, bb = (tid >> 6) & 1, e = tid & 63;
        float mn = 1e30f, off = -1e30f, dg = -1e30f;
        for (int k = 0; k < 128; ++k) {
            int o = l * 16384 + (bb * 128 + k) * 64 + e;
            mn  = fminf(mn,  p.Pmin[o]);
            off = fmaxf(off, p.Poff[o]);
            dg  = fmaxf(dg,  p.Pdg[o]);
        }
        sm_mn[tid] = mn; sm_off[tid] = off; sm_dg[tid] = dg;
    }
    __syncthreads();
    // stage 2: per-layer val = |global max_diag - global min|
    if (tid < 4) {
        float gmx = -1e30f, gmn = 1e30f;
        for (int i2 = 0; i2 < 128; ++i2) {
            gmx = fmaxf(gmx, sm_dg[tid * 128 + i2]);
            gmn = fminf(gmn, sm_mn[tid * 128 + i2]);
        }
        vals[tid] = fabsf(gmx - gmn);
    }
    __syncthreads();
    // stage 3: partial GEMV  (tid = bb*256 + cc*8 + pp)
    {
        int bb = tid >> 8, cc = (tid >> 3) & 31, pp = tid & 7;
        float a2 = 0.0f;
        for (int l = 0; l < 4; ++l) {
            float val = vals[l];
            const float* Wr = p.opW + l * 4096 + cc * 128;
            int base = l * 128 + bb * 64;
            for (int j = pp * 16; j < pp * 16 + 16; ++j) {
                float pv;
                if (j < 64) pv = sm_dg[base + j];
                else        pv = fmaxf(sm_off[base + j - 64], sm_dg[base + j - 64] - val);
                a2 = fmaf(Wr[j], pv, a2);
            }
        }
        psum[tid] = a2;
    }
    __syncthreads();
    if (tid < 64) {
        int bb = tid >> 5, cc = tid & 31;
        float a2 = 0.0f;
        for (int l = 0; l < 4; ++l) a2 += p.opb[l * 32 + cc];
        for (int pp = 0; pp < 8; ++pp) a2 += psum[bb * 256 + cc * 8 + pp];
        scores_s[tid] = a2;
    }
    __syncthreads();
    if (tid < 32) {
        float sA = scores_s[tid], sB = scores_s[32 + tid];
        float mu = 0.5f * (sA + sB);
        float va = 0.5f * ((sA - mu) * (sA - mu) + (sB - mu) * (sB - mu));
        float inv = rsqrtf(va + EPS);
        p.out[tid]      = (sA - mu) * inv;
        p.out[32 + tid] = (sB - mu) * inv;
    }
}

extern "C" void kernel_launch(void* const* d_in, const int* in_sizes, int n_in,
                              void* d_out, int out_size, void* d_ws, size_t ws_size,
                              hipStream_t stream) {
    Params prm;
    prm.ei    = (const int*)d_in[0];
    prm.batch = (const int*)d_in[1];
    prm.E     = in_sizes[0] / 2;
    prm.W0    = (const float*)d_in[2];
    prm.b0    = (const float*)d_in[3];
    prm.Ws    = (const float*)d_in[4];
    prm.bs    = (const float*)d_in[5];
    prm.ln_g  = (const float*)d_in[6];
    prm.ln_b  = (const float*)d_in[7];
    prm.fW0   = (const float*)d_in[8];
    prm.fb0   = (const float*)d_in[9];
    prm.fWs   = (const float*)d_in[10];
    prm.fbs   = (const float*)d_in[11];
    prm.fln_g = (const float*)d_in[12];
    prm.fln_b = (const float*)d_in[13];
    prm.opW   = (const float*)d_in[14];
    prm.opb   = (const float*)d_in[15];

    float* ws = (float*)d_ws;
    prm.h0    = ws;                   // 131072
    prm.q0    = prm.h0   + 131072;
    prm.h1    = prm.q0   + 131072;
    prm.q1    = prm.h1   + 131072;
    prm.Pmin  = prm.q1   + 131072;    // 4*16384
    prm.Poff  = prm.Pmin + 65536;
    prm.Pdg   = prm.Poff + 65536;
    prm.bar   = (int*)(prm.Pdg + 65536);  // 1153 ints
    prm.out   = (float*)d_out;

    void* args[] = { &prm };
    hipLaunchCooperativeKernel((void*)fused_all, dim3(256), dim3(512), args, 0, stream);
}

// Round 7
// 228.852 us; speedup vs baseline: 2.1186x; 1.0854x over previous
//
#include <hip/hip_runtime.h>
#include <math.h>

// Shapes fixed by the reference: B=2, N=32, L=4, ED=64, H=4, HD=16
#define EPS 1e-5f
#define MAGIC 0x13579BDF

#define AG_LOAD(p)     __hip_atomic_load((p), __ATOMIC_RELAXED, __HIP_MEMORY_SCOPE_AGENT)
#define AG_STORE(p, v) __hip_atomic_store((p), (v), __ATOMIC_RELAXED, __HIP_MEMORY_SCOPE_AGENT)

struct Params {
    const int* ei; const int* batch; int E;
    const float* W0; const float* b0; const float* Ws; const float* bs;
    const float* ln_g; const float* ln_b;
    const float* fW0; const float* fb0; const float* fWs; const float* fbs;
    const float* fln_g; const float* fln_b;
    const float* opW; const float* opb;
    float* h0; float* q0;        // layer-2 h/q
    float* h1; float* q1;        // layer-1/3 h/q
    float* Pmin; float* Poff; float* Pdg;  // [4 layers][256 blocks][64 e]
    int* bar;                    // tree-barrier state
    float* out;                  // 64
};

// Tree grid barrier with ZERO cache maintenance. All cross-XCD data (h/q,
// pool partials, barrier words) uses agent-scope relaxed atomics, which are
// device-coherent at the LLC — so the barrier needs no wbl2/inv at all.
// Visibility ordering: __syncthreads() at entry drains each wave's vmcnt(0)
// (compiler emits s_waitcnt vmcnt(0) before s_barrier), so all sc-stores are
// LLC-visible before any lane arrives.
// Layout (ints, monotonic, never reset):
//   bar[site*256 + g*16] : group counters (site<4, g<16), line-padded
//   bar[1024 + site*16]  : root counter
//   bar[1088 + site*16]  : release word
//   bar[1152]            : ready flag (MAGIC after block 0 zeroes the above)
__device__ __forceinline__ void gbar(int* bar, int site, bool wait) {
    __syncthreads();   // drains vmcnt(0) per wave -> sc-stores visible at LLC
    if (threadIdx.x == 0) {
        if (site == 0) {   // gate first use on block 0's init
            while (AG_LOAD(&bar[1152]) != MAGIC) __builtin_amdgcn_s_sleep(1);
        }
        int g = blockIdx.x & 15;
        int r = __hip_atomic_fetch_add(&bar[site * 256 + g * 16], 1,
                                       __ATOMIC_RELAXED, __HIP_MEMORY_SCOPE_AGENT);
        if (r == 15) {
            int r2 = __hip_atomic_fetch_add(&bar[1024 + site * 16], 1,
                                            __ATOMIC_RELAXED, __HIP_MEMORY_SCOPE_AGENT);
            if (r2 == 15)
                AG_STORE(&bar[1088 + site * 16], 1);
        }
        if (wait) {
            while (AG_LOAD(&bar[1088 + site * 16]) == 0) __builtin_amdgcn_s_sleep(1);
        }
    }
    __syncthreads();
}

// Grid: 256 blocks x 512 threads = one thread per (row, channel).
// A row (b,xi,y) is exactly one wave (64 lanes = 64 channels).
__launch_bounds__(512, 1)
__global__ void fused_all(Params p) {
    const int tid  = threadIdx.x;
    const int blk  = blockIdx.x;
    const int gtid = blk * 512 + tid;

    const int row = gtid >> 6;            // (b*32+xi)*32 + y
    const int c   = gtid & 63;            // head*16 + d
    const int d   = c & 15;
    const int rl  = tid >> 6;             // row-in-block 0..7
    const int y   = row & 31;
    const int b   = row >> 10;

    const int r0      = blk * 8;
    const int b_blk   = r0 >> 10;
    const int xi_blk  = (r0 >> 5) & 31;
    const int y0      = r0 & 31;          // 0,8,16,24
    const int rld     = xi_blk - y0;      // diag row-in-block if in [0,8)
    const int slab_off = (b_blk * 1024 + xi_blk * 32) * 64;

    __shared__ float qx_s[2048];          // q slab (b_blk, xi_blk, a=0..31)
    __shared__ float hx_s[2048];
    __shared__ float xrow[8][64];         // current x for our 8 rows
    __shared__ float xu_s[8][64];
    __shared__ float xslab[32];           // layer-0: adj[b_blk, xi_blk, a]
    __shared__ float yslab[256];          // layer-0: adj[b_blk, a, y0+j] at [a*8+j]
    // epilogue scratch (block 0)
    __shared__ float sm_mn[512], sm_off[512], sm_dg[512];
    __shared__ float psum[512];
    __shared__ float vals[4];
    __shared__ float scores_s[64];

    // ---- init barrier state (block 0; sc-stores drained by later sync) ----
    if (blk == 0) {
        for (int i = tid; i < 1152; i += 512) AG_STORE(&p.bar[i], 0);
        __syncthreads();   // drain zero-stores to LLC
        if (tid == 0) AG_STORE(&p.bar[1152], MAGIC);
    }

    // ---- layer-0 adjacency slabs: block-local redundant edge scan ----
    if (tid < 32)  xslab[tid] = 0.0f;
    if (tid < 256) yslab[tid] = 0.0f;
    __syncthreads();
    for (int e2 = tid; e2 < p.E; e2 += 512) {
        int e0 = p.ei[e2], e1 = p.ei[p.E + e2];
        int g  = p.batch[e0];
        if (g == b_blk) {
            int ls = e0 - g * 32, ld = e1 - g * 32;
            if (ls == xi_blk) atomicAdd(&xslab[ld], 1.0f);
            unsigned dy = (unsigned)(ld - y0);
            if (dy < 8u) atomicAdd(&yslab[ls * 8 + dy], 1.0f);
        }
    }
    __syncthreads();
    if (tid == 0) xslab[xi_blk] = 2.0f;
    if (tid < 8)  yslab[(y0 + tid) * 8 + tid] = 2.0f;   // diag a==y
    __syncthreads();

    // ======================= LAYER 0 (no grid barrier) =======================
    {
        const float gl = p.ln_g[d], bl = p.ln_b[d];

        // closed-form LN16 of the rank-1 h = W*v + b : per-head stats
        float Wc = p.W0[c], bc = p.b0[c];
        float sW = Wc, sB = bc;
        #pragma unroll
        for (int m = 1; m < 16; m <<= 1) {
            sW += __shfl_xor(sW, m, 16);
            sB += __shfl_xor(sB, m, 16);
        }
        float Ac = Wc - sW * 0.0625f;
        float Bc = bc - sB * 0.0625f;
        float sAA = Ac * Ac, sAB = Ac * Bc, sBB = Bc * Bc;
        #pragma unroll
        for (int m = 1; m < 16; m <<= 1) {
            sAA += __shfl_xor(sAA, m, 16);
            sAB += __shfl_xor(sAB, m, 16);
            sBB += __shfl_xor(sBB, m, 16);
        }
        const float varW = sAA * 0.0625f, covWB = sAB * 0.0625f, varB = sBB * 0.0625f;
        const float adjv = xslab[y];

        float sarr[32], narr[32];
        #pragma unroll
        for (int a = 0; a < 32; ++a) {
            float vx = xslab[a];
            float vy = yslab[a * 8 + rl];
            float hx = fmaf(Wc, vx, bc);
            float hy = fmaf(Wc, vy, bc);
            float qx = fmaf(Ac, vx, Bc) *
                       rsqrtf(fmaf(fmaf(varW, vx, 2.0f * covWB), vx, varB) + EPS) * gl + bl;
            float qy = fmaf(Ac, vy, Bc) *
                       rsqrtf(fmaf(fmaf(varW, vy, 2.0f * covWB), vy, varB) + EPS) * gl + bl;
            float rdot = qx * qy;
            float pp   = hx * hy;
            float rsum = pp, rsq = pp * pp;
            #pragma unroll
            for (int m = 1; m < 16; m <<= 1) {
                rdot += __shfl_xor(rdot, m, 16);
                rsum += __shfl_xor(rsum, m, 16);
                rsq  += __shfl_xor(rsq,  m, 16);
            }
            sarr[a] = rdot * 0.25f;
            float pmean = rsum * 0.0625f;
            float pvar  = fmaxf(rsq * 0.0625f - pmean * pmean, 0.0f);
            narr[a] = (pp - pmean) * rsqrtf(pvar + EPS) * gl;
        }
        float mx = sarr[0];
        #pragma unroll
        for (int a = 1; a < 32; ++a) mx = fmaxf(mx, sarr[a]);
        float lsum = 0.0f, asum = 0.0f;
        #pragma unroll
        for (int a = 0; a < 32; ++a) {
            float ee = __expf(sarr[a] - mx);
            lsum += ee;
            asum = fmaf(ee, narr[a], asum);
        }
        xu_s[rl][c] = asum / lsum + bl;   // wave-local

        // fin (K=65) + LN64
        const float* Wr2 = p.fW0 + c * 65;
        float acc2 = fmaf(Wr2[0], adjv, p.fb0[c]);
        #pragma unroll
        for (int j = 0; j < 64; ++j) acc2 = fmaf(Wr2[1 + j], xu_s[rl][j], acc2);
        float t1 = acc2;
        #pragma unroll
        for (int m = 1; m < 64; m <<= 1) t1 += __shfl_xor(t1, m, 64);
        float mu = t1 * (1.0f / 64.0f);
        float dv2 = acc2 - mu;
        float t2 = dv2 * dv2;
        #pragma unroll
        for (int m = 1; m < 64; m <<= 1) t2 += __shfl_xor(t2, m, 64);
        xrow[rl][c] = dv2 * rsqrtf(t2 * (1.0f / 64.0f) + EPS) * p.fln_g[c] + p.fln_b[c];
    }
    __syncthreads();
    // layer-0 pool partial over our 8 rows, straight from LDS (sc-stores)
    if (tid < 64) {
        float mn = 1e30f, off = -1e30f, dg = -1e30f;
        #pragma unroll
        for (int r2 = 0; r2 < 8; ++r2) {
            float v = xrow[r2][tid];
            mn = fminf(mn, v);
            if (r2 == rld) dg = v; else off = fmaxf(off, v);
        }
        int o = blk * 64 + tid;
        AG_STORE(&p.Pmin[o], mn); AG_STORE(&p.Poff[o], off); AG_STORE(&p.Pdg[o], dg);
    }

    // ======================= LAYERS 1..3 =======================
    for (int layer = 1; layer < 4; ++layer) {
        const float* W     = p.Ws  + (layer - 1) * 4096;
        const float* bw    = p.bs  + (layer - 1) * 64;
        const float* fW    = p.fWs + (layer - 1) * 8192;
        const float* fb    = p.fbs + (layer - 1) * 64;
        const float* lg    = p.ln_g  + layer * 16;
        const float* lb    = p.ln_b  + layer * 16;
        const float* fg    = p.fln_g + layer * 64;
        const float* fbeta = p.fln_b + layer * 64;
        float* hbuf = (layer & 1) ? p.h1 : p.h0;
        float* qbuf = (layer & 1) ? p.q1 : p.q0;

        // ---- Phase L: h = x@W.T + b ; q = LN16(h). Wave-local. ----
        float acc = bw[c];
        {
            const float* Wr = W + c * 64;
            #pragma unroll
            for (int j = 0; j < 64; ++j) acc = fmaf(Wr[j], xrow[rl][j], acc);
        }
        AG_STORE(&hbuf[gtid], acc);          // device-coherent publish
        float s1 = acc;
        #pragma unroll
        for (int m = 1; m < 16; m <<= 1) s1 += __shfl_xor(s1, m, 16);
        float mean = s1 * 0.0625f;
        float dv = acc - mean;
        float s2 = dv * dv;
        #pragma unroll
        for (int m = 1; m < 16; m <<= 1) s2 += __shfl_xor(s2, m, 16);
        AG_STORE(&qbuf[gtid], dv * rsqrtf(s2 * 0.0625f + EPS) * lg[d] + lb[d]);

        gbar(p.bar, layer - 1, true);   // the ONE barrier per layer (counters only)

        // ---- Phase A: attention. Batch all device-coherent loads first. ----
        const float* qy = qbuf + (b * 1024 + y) * 64 + c;   // + a*2048
        const float* hy = hbuf + (b * 1024 + y) * 64 + c;
        float qyv[32], hyv[32];
        #pragma unroll
        for (int a = 0; a < 32; ++a) {
            qyv[a] = AG_LOAD(qy + a * 2048);
            hyv[a] = AG_LOAD(hy + a * 2048);
        }
        float qsl[4], hsl[4];
        #pragma unroll
        for (int k = 0; k < 4; ++k) {
            qsl[k] = AG_LOAD(qbuf + slab_off + tid + k * 512);
            hsl[k] = AG_LOAD(hbuf + slab_off + tid + k * 512);
        }
        #pragma unroll
        for (int k = 0; k < 4; ++k) {
            qx_s[tid + k * 512] = qsl[k];
            hx_s[tid + k * 512] = hsl[k];
        }
        __syncthreads();

        const float gl = lg[d], bl = lb[d];
        float sarr[32], narr[32];
        #pragma unroll
        for (int a = 0; a < 32; ++a) {
            float qxv = qx_s[a * 64 + c];
            float hxv = hx_s[a * 64 + c];
            float rdot = qxv * qyv[a];
            float pp   = hxv * hyv[a];
            float rsum = pp, rsq = pp * pp;
            #pragma unroll
            for (int m = 1; m < 16; m <<= 1) {
                rdot += __shfl_xor(rdot, m, 16);
                rsum += __shfl_xor(rsum, m, 16);
                rsq  += __shfl_xor(rsq,  m, 16);
            }
            sarr[a] = rdot * 0.25f;
            float pmean = rsum * 0.0625f;
            float pvar  = fmaxf(rsq * 0.0625f - pmean * pmean, 0.0f);
            narr[a] = (pp - pmean) * rsqrtf(pvar + EPS) * gl;
        }
        float mx = sarr[0];
        #pragma unroll
        for (int a = 1; a < 32; ++a) mx = fmaxf(mx, sarr[a]);
        float lsum = 0.0f, asum = 0.0f;
        #pragma unroll
        for (int a = 0; a < 32; ++a) {
            float ee = __expf(sarr[a] - mx);
            lsum += ee;
            asum = fmaf(ee, narr[a], asum);
        }
        xu_s[rl][c] = asum / lsum + bl;   // wave-local

        // ---- fin: y = concat([x, xu]) @ fW.T + fb, LN64. Wave-local. ----
        const float* Wr2 = fW + c * 128;
        float acc2 = fb[c];
        #pragma unroll
        for (int j = 0; j < 64; ++j) acc2 = fmaf(Wr2[j], xrow[rl][j], acc2);
        #pragma unroll
        for (int j = 0; j < 64; ++j) acc2 = fmaf(Wr2[64 + j], xu_s[rl][j], acc2);
        float t1 = acc2;
        #pragma unroll
        for (int m = 1; m < 64; m <<= 1) t1 += __shfl_xor(t1, m, 64);
        float mu = t1 * (1.0f / 64.0f);
        float dv2 = acc2 - mu;
        float t2 = dv2 * dv2;
        #pragma unroll
        for (int m = 1; m < 64; m <<= 1) t2 += __shfl_xor(t2, m, 64);
        float xnew = dv2 * rsqrtf(t2 * (1.0f / 64.0f) + EPS) * fg[c] + fbeta[c];
        xrow[rl][c] = xnew;            // wave-local write
        __syncthreads();               // publish xrow to wave 0 for pooling

        // pool partial for this layer, straight from LDS (uniform, all blocks)
        if (tid < 64) {
            float mn = 1e30f, off = -1e30f, dg = -1e30f;
            #pragma unroll
            for (int r2 = 0; r2 < 8; ++r2) {
                float v = xrow[r2][tid];
                mn = fminf(mn, v);
                if (r2 == rld) dg = v; else off = fmaxf(off, v);
            }
            int o = layer * 16384 + blk * 64 + tid;
            AG_STORE(&p.Pmin[o], mn); AG_STORE(&p.Poff[o], off); AG_STORE(&p.Pdg[o], dg);
        }
    }

    // ---- final barrier: non-zero blocks arrive and exit ----
    gbar(p.bar, 3, blk == 0);
    if (blk != 0) return;

    // ================= epilogue (block 0 only) =================
    // stage 1: reduce 128 block-partials per (layer, graph, e) — coalesced
    {
        int l = tid >> 7, bb = (tid >> 6) & 1, e = tid & 63;
        float mn = 1e30f, off = -1e30f, dg = -1e30f;
        #pragma unroll 8
        for (int k = 0; k < 128; ++k) {
            int o = l * 16384 + (bb * 128 + k) * 64 + e;
            mn  = fminf(mn,  AG_LOAD(&p.Pmin[o]));
            off = fmaxf(off, AG_LOAD(&p.Poff[o]));
            dg  = fmaxf(dg,  AG_LOAD(&p.Pdg[o]));
        }
        sm_mn[tid] = mn; sm_off[tid] = off; sm_dg[tid] = dg;
    }
    __syncthreads();
    // stage 2: per-layer val = |global max_diag - global min|
    if (tid < 4) {
        float gmx = -1e30f, gmn = 1e30f;
        for (int i2 = 0; i2 < 128; ++i2) {
            gmx = fmaxf(gmx, sm_dg[tid * 128 + i2]);
            gmn = fminf(gmn, sm_mn[tid * 128 + i2]);
        }
        vals[tid] = fabsf(gmx - gmn);
    }
    __syncthreads();
    // stage 3: partial GEMV  (tid = bb*256 + cc*8 + pp)
    {
        int bb = tid >> 8, cc = (tid >> 3) & 31, pp = tid & 7;
        float a2 = 0.0f;
        for (int l = 0; l < 4; ++l) {
            float val = vals[l];
            const float* Wr = p.opW + l * 4096 + cc * 128;
            int base = l * 128 + bb * 64;
            for (int j = pp * 16; j < pp * 16 + 16; ++j) {
                float pv;
                if (j < 64) pv = sm_dg[base + j];
                else        pv = fmaxf(sm_off[base + j - 64], sm_dg[base + j - 64] - val);
                a2 = fmaf(Wr[j], pv, a2);
            }
        }
        psum[tid] = a2;
    }
    __syncthreads();
    if (tid < 64) {
        int bb = tid >> 5, cc = tid & 31;
        float a2 = 0.0f;
        for (int l = 0; l < 4; ++l) a2 += p.opb[l * 32 + cc];
        for (int pp = 0; pp < 8; ++pp) a2 += psum[bb * 256 + cc * 8 + pp];
        scores_s[tid] = a2;
    }
    __syncthreads();
    if (tid < 32) {
        float sA = scores_s[tid], sB = scores_s[32 + tid];
        float mu = 0.5f * (sA + sB);
        float va = 0.5f * ((sA - mu) * (sA - mu) + (sB - mu) * (sB - mu));
        float inv = rsqrtf(va + EPS);
        p.out[tid]      = (sA - mu) * inv;
        p.out[32 + tid] = (sB - mu) * inv;
    }
}

extern "C" void kernel_launch(void* const* d_in, const int* in_sizes, int n_in,
                              void* d_out, int out_size, void* d_ws, size_t ws_size,
                              hipStream_t stream) {
    Params prm;
    prm.ei    = (const int*)d_in[0];
    prm.batch = (const int*)d_in[1];
    prm.E     = in_sizes[0] / 2;
    prm.W0    = (const float*)d_in[2];
    prm.b0    = (const float*)d_in[3];
    prm.Ws    = (const float*)d_in[4];
    prm.bs    = (const float*)d_in[5];
    prm.ln_g  = (const float*)d_in[6];
    prm.ln_b  = (const float*)d_in[7];
    prm.fW0   = (const float*)d_in[8];
    prm.fb0   = (const float*)d_in[9];
    prm.fWs   = (const float*)d_in[10];
    prm.fbs   = (const float*)d_in[11];
    prm.fln_g = (const float*)d_in[12];
    prm.fln_b = (const float*)d_in[13];
    prm.opW   = (const float*)d_in[14];
    prm.opb   = (const float*)d_in[15];

    float* ws = (float*)d_ws;
    prm.h0    = ws;                   // 131072
    prm.q0    = prm.h0   + 131072;
    prm.h1    = prm.q0   + 131072;
    prm.q1    = prm.h1   + 131072;
    prm.Pmin  = prm.q1   + 131072;    // 4*16384
    prm.Poff  = prm.Pmin + 65536;
    prm.Pdg   = prm.Poff + 65536;
    prm.bar   = (int*)(prm.Pdg + 65536);  // 1153 ints
    prm.out   = (float*)d_out;

    void* args[] = { &prm };
    hipLaunchCooperativeKernel((void*)fused_all, dim3(256), dim3(512), args, 0, stream);
}

// Round 8
// 196.663 us; speedup vs baseline: 2.4653x; 1.1637x over previous
//
#include <hip/hip_runtime.h>
#include <math.h>

// Shapes fixed by the reference: B=2, N=32, L=4, ED=64, H=4, HD=16
#define EPS 1e-5f

#define AG_LOAD(p)     __hip_atomic_load((p), __ATOMIC_RELAXED, __HIP_MEMORY_SCOPE_AGENT)
#define AG_STORE(p, v) __hip_atomic_store((p), (v), __ATOMIC_RELAXED, __HIP_MEMORY_SCOPE_AGENT)

struct Params {
    const int* ei; const int* batch; int E;
    const float* W0; const float* b0; const float* Ws; const float* bs;
    const float* ln_g; const float* ln_b;
    const float* fW0; const float* fb0; const float* fWs; const float* fbs;
    const float* fln_g; const float* fln_b;
    const float* opW; const float* opb;
    float* hA; float* qA;    // h/q for layers 1 and 3
    float* hB; float* qB;    // h/q for layer 2
    float* xbuf;             // x rows, block-owned (same block writes & reads)
    float* Pmin; float* Poff; float* Pdg;  // [4 layers][256 blocks][64 e]
    int* bar;                // tail counter (zeroed by k0)
    float* out;              // 64
};

// ---------------------------------------------------------------------------
// K0: adjacency slabs + closed-form layer 0 + pool partial 0 + lin -> h1/q1.
// 256 blocks x 512 threads; block owns 8 rows (one (b, xi) slab quarter).
__launch_bounds__(512, 1)
__global__ void k0(Params p) {
    const int tid  = threadIdx.x;
    const int blk  = blockIdx.x;
    const int gtid = blk * 512 + tid;
    const int c    = gtid & 63;
    const int d    = c & 15;
    const int rl   = tid >> 6;
    const int row  = gtid >> 6;
    const int y    = row & 31;
    const int r0     = blk * 8;
    const int b_blk  = r0 >> 10;
    const int xi_blk = (r0 >> 5) & 31;
    const int y0     = r0 & 31;
    const int rld    = xi_blk - y0;

    __shared__ float xslab[32];      // adj[b_blk, xi_blk, a]
    __shared__ float yslab[256];     // adj[b_blk, a, y0+j] at [a*8+j]
    __shared__ float xu_s[8][64];
    __shared__ float xrow[8][64];

    if (blk == 0 && tid == 0) p.bar[0] = 0;   // tail counter for k3

    // block-local redundant edge scan
    if (tid < 32)  xslab[tid] = 0.0f;
    if (tid < 256) yslab[tid] = 0.0f;
    __syncthreads();
    for (int e2 = tid; e2 < p.E; e2 += 512) {
        int e0 = p.ei[e2], e1 = p.ei[p.E + e2];
        int g  = p.batch[e0];
        if (g == b_blk) {
            int ls = e0 - g * 32, ld = e1 - g * 32;
            if (ls == xi_blk) atomicAdd(&xslab[ld], 1.0f);
            unsigned dy = (unsigned)(ld - y0);
            if (dy < 8u) atomicAdd(&yslab[ls * 8 + dy], 1.0f);
        }
    }
    __syncthreads();
    if (tid == 0) xslab[xi_blk] = 2.0f;
    if (tid < 8)  yslab[(y0 + tid) * 8 + tid] = 2.0f;   // diag a==y
    __syncthreads();

    // ---- layer 0, closed form (h = W*v + b is rank-1 in adj scalar v) ----
    {
        const float gl = p.ln_g[d], bl = p.ln_b[d];
        float Wc = p.W0[c], bc = p.b0[c];
        float sW = Wc, sB = bc;
        #pragma unroll
        for (int m = 1; m < 16; m <<= 1) {
            sW += __shfl_xor(sW, m, 16);
            sB += __shfl_xor(sB, m, 16);
        }
        float Ac = Wc - sW * 0.0625f;
        float Bc = bc - sB * 0.0625f;
        float sAA = Ac * Ac, sAB = Ac * Bc, sBB = Bc * Bc;
        #pragma unroll
        for (int m = 1; m < 16; m <<= 1) {
            sAA += __shfl_xor(sAA, m, 16);
            sAB += __shfl_xor(sAB, m, 16);
            sBB += __shfl_xor(sBB, m, 16);
        }
        const float varW = sAA * 0.0625f, covWB = sAB * 0.0625f, varB = sBB * 0.0625f;
        const float adjv = xslab[y];

        float sarr[32], narr[32];
        #pragma unroll
        for (int a = 0; a < 32; ++a) {
            float vx = xslab[a];
            float vy = yslab[a * 8 + rl];
            float hx = fmaf(Wc, vx, bc);
            float hy = fmaf(Wc, vy, bc);
            float qx = fmaf(Ac, vx, Bc) *
                       rsqrtf(fmaf(fmaf(varW, vx, 2.0f * covWB), vx, varB) + EPS) * gl + bl;
            float qy = fmaf(Ac, vy, Bc) *
                       rsqrtf(fmaf(fmaf(varW, vy, 2.0f * covWB), vy, varB) + EPS) * gl + bl;
            float rdot = qx * qy;
            float pp   = hx * hy;
            float rsum = pp, rsq = pp * pp;
            #pragma unroll
            for (int m = 1; m < 16; m <<= 1) {
                rdot += __shfl_xor(rdot, m, 16);
                rsum += __shfl_xor(rsum, m, 16);
                rsq  += __shfl_xor(rsq,  m, 16);
            }
            sarr[a] = rdot * 0.25f;
            float pmean = rsum * 0.0625f;
            float pvar  = fmaxf(rsq * 0.0625f - pmean * pmean, 0.0f);
            narr[a] = (pp - pmean) * rsqrtf(pvar + EPS) * gl;
        }
        float mx = sarr[0];
        #pragma unroll
        for (int a = 1; a < 32; ++a) mx = fmaxf(mx, sarr[a]);
        float lsum = 0.0f, asum = 0.0f;
        #pragma unroll
        for (int a = 0; a < 32; ++a) {
            float ee = __expf(sarr[a] - mx);
            lsum += ee;
            asum = fmaf(ee, narr[a], asum);
        }
        xu_s[rl][c] = asum / lsum + bl;   // wave-local

        // fin (K=65) + LN64
        const float* Wr2 = p.fW0 + c * 65;
        float acc2 = fmaf(Wr2[0], adjv, p.fb0[c]);
        #pragma unroll
        for (int j = 0; j < 64; ++j) acc2 = fmaf(Wr2[1 + j], xu_s[rl][j], acc2);
        float t1 = acc2;
        #pragma unroll
        for (int m = 1; m < 64; m <<= 1) t1 += __shfl_xor(t1, m, 64);
        float mu = t1 * (1.0f / 64.0f);
        float dv2 = acc2 - mu;
        float t2 = dv2 * dv2;
        #pragma unroll
        for (int m = 1; m < 64; m <<= 1) t2 += __shfl_xor(t2, m, 64);
        float xnew = dv2 * rsqrtf(t2 * (1.0f / 64.0f) + EPS) * p.fln_g[c] + p.fln_b[c];
        xrow[rl][c]  = xnew;
        p.xbuf[gtid] = xnew;
    }
    __syncthreads();

    // pool partial for x1 (slot 0)
    if (tid < 64) {
        float mn = 1e30f, off = -1e30f, dg = -1e30f;
        #pragma unroll
        for (int r2 = 0; r2 < 8; ++r2) {
            float v = xrow[r2][tid];
            mn = fminf(mn, v);
            if (r2 == rld) dg = v; else off = fmaxf(off, v);
        }
        int o = blk * 64 + tid;
        p.Pmin[o] = mn; p.Poff[o] = off; p.Pdg[o] = dg;
    }

    // lin layer 1: h1 = x1 @ Ws[0].T + bs[0]; q1 = LN16(h1) with ln[1]
    {
        const float* Wr = p.Ws + c * 64;
        float acc = p.bs[c];
        #pragma unroll
        for (int j = 0; j < 64; ++j) acc = fmaf(Wr[j], xrow[rl][j], acc);
        p.hA[gtid] = acc;
        float s1 = acc;
        #pragma unroll
        for (int m = 1; m < 16; m <<= 1) s1 += __shfl_xor(s1, m, 16);
        float mean = s1 * 0.0625f;
        float dv = acc - mean;
        float s2 = dv * dv;
        #pragma unroll
        for (int m = 1; m < 16; m <<= 1) s2 += __shfl_xor(s2, m, 16);
        p.qA[gtid] = dv * rsqrtf(s2 * 0.0625f + EPS) * p.ln_g[16 + d] + p.ln_b[16 + d];
    }
}

// ---------------------------------------------------------------------------
// K(layer): attention + fin for `layer` (1..3), pool partial, then either
// lin->h/q for layer+1 (layer<3) or the tail-block epilogue (layer==3).
__launch_bounds__(512, 1)
__global__ void klayer(Params p, int layer, int is_last) {
    const int tid  = threadIdx.x;
    const int blk  = blockIdx.x;
    const int gtid = blk * 512 + tid;
    const int c    = gtid & 63;
    const int d    = c & 15;
    const int rl   = tid >> 6;
    const int row  = gtid >> 6;
    const int y    = row & 31;
    const int b    = row >> 10;
    const int r0     = blk * 8;
    const int b_blk  = r0 >> 10;
    const int xi_blk = (r0 >> 5) & 31;
    const int y0     = r0 & 31;
    const int rld    = xi_blk - y0;
    const int slab_off = (b_blk * 1024 + xi_blk * 32) * 64;

    const float* hin = (layer == 2) ? p.hB : p.hA;
    const float* qin = (layer == 2) ? p.qB : p.qA;
    float* hout = (layer == 1) ? p.hB : p.hA;   // layer2 overwrites hA (h1 dead)
    float* qout = (layer == 1) ? p.qB : p.qA;

    __shared__ float qx_s[2048], hx_s[2048];
    __shared__ float xrow[8][64], xu_s[8][64];
    __shared__ float sm_mn[512], sm_off[512], sm_dg[512];
    __shared__ float psum[512];
    __shared__ float vals[4];
    __shared__ float scores_s[64];
    __shared__ int tailflag;

    // issue all global loads up front
    float xv = p.xbuf[gtid];
    float4 qsl = ((const float4*)(qin + slab_off))[tid];
    float4 hsl = ((const float4*)(hin + slab_off))[tid];
    const float* qy = qin + (b * 1024 + y) * 64 + c;   // + a*2048
    const float* hy = hin + (b * 1024 + y) * 64 + c;
    float qyv[32], hyv[32];
    #pragma unroll
    for (int a = 0; a < 32; ++a) {
        qyv[a] = qy[a * 2048];
        hyv[a] = hy[a * 2048];
    }
    xrow[rl][c] = xv;
    ((float4*)qx_s)[tid] = qsl;
    ((float4*)hx_s)[tid] = hsl;
    __syncthreads();

    const float gl = p.ln_g[layer * 16 + d], bl = p.ln_b[layer * 16 + d];
    float sarr[32], narr[32];
    #pragma unroll
    for (int a = 0; a < 32; ++a) {
        float qxv = qx_s[a * 64 + c];
        float hxv = hx_s[a * 64 + c];
        float rdot = qxv * qyv[a];
        float pp   = hxv * hyv[a];
        float rsum = pp, rsq = pp * pp;
        #pragma unroll
        for (int m = 1; m < 16; m <<= 1) {
            rdot += __shfl_xor(rdot, m, 16);
            rsum += __shfl_xor(rsum, m, 16);
            rsq  += __shfl_xor(rsq,  m, 16);
        }
        sarr[a] = rdot * 0.25f;
        float pmean = rsum * 0.0625f;
        float pvar  = fmaxf(rsq * 0.0625f - pmean * pmean, 0.0f);
        narr[a] = (pp - pmean) * rsqrtf(pvar + EPS) * gl;
    }
    float mx = sarr[0];
    #pragma unroll
    for (int a = 1; a < 32; ++a) mx = fmaxf(mx, sarr[a]);
    float lsum = 0.0f, asum = 0.0f;
    #pragma unroll
    for (int a = 0; a < 32; ++a) {
        float ee = __expf(sarr[a] - mx);
        lsum += ee;
        asum = fmaf(ee, narr[a], asum);
    }
    xu_s[rl][c] = asum / lsum + bl;   // wave-local

    // fin: y = concat([x, xu]) @ fW.T + fb, LN64
    const float* Wr2 = p.fWs + (layer - 1) * 8192 + c * 128;
    float acc2 = p.fbs[(layer - 1) * 64 + c];
    #pragma unroll
    for (int j = 0; j < 64; ++j) acc2 = fmaf(Wr2[j], xrow[rl][j], acc2);
    #pragma unroll
    for (int j = 0; j < 64; ++j) acc2 = fmaf(Wr2[64 + j], xu_s[rl][j], acc2);
    float t1 = acc2;
    #pragma unroll
    for (int m = 1; m < 64; m <<= 1) t1 += __shfl_xor(t1, m, 64);
    float mu = t1 * (1.0f / 64.0f);
    float dv2 = acc2 - mu;
    float t2 = dv2 * dv2;
    #pragma unroll
    for (int m = 1; m < 64; m <<= 1) t2 += __shfl_xor(t2, m, 64);
    float xnew = dv2 * rsqrtf(t2 * (1.0f / 64.0f) + EPS) *
                 p.fln_g[layer * 64 + c] + p.fln_b[layer * 64 + c];
    __syncthreads();          // xrow reuse hazard (we re-write it next)
    xrow[rl][c] = xnew;
    if (!is_last) p.xbuf[gtid] = xnew;
    __syncthreads();

    // pool partial for this layer
    if (tid < 64) {
        float mn = 1e30f, off = -1e30f, dg = -1e30f;
        #pragma unroll
        for (int r2 = 0; r2 < 8; ++r2) {
            float v = xrow[r2][tid];
            mn = fminf(mn, v);
            if (r2 == rld) dg = v; else off = fmaxf(off, v);
        }
        int o = layer * 16384 + blk * 64 + tid;
        if (is_last) {   // must be LLC-visible within this kernel (tail reads)
            AG_STORE(&p.Pmin[o], mn); AG_STORE(&p.Poff[o], off); AG_STORE(&p.Pdg[o], dg);
        } else {
            p.Pmin[o] = mn; p.Poff[o] = off; p.Pdg[o] = dg;
        }
    }

    if (!is_last) {
        // lin layer+1: h = x @ Ws[layer].T + bs[layer]; q = LN16 with ln[layer+1]
        const float* Wr = p.Ws + layer * 4096 + c * 64;
        float acc = p.bs[layer * 64 + c];
        #pragma unroll
        for (int j = 0; j < 64; ++j) acc = fmaf(Wr[j], xrow[rl][j], acc);
        hout[gtid] = acc;
        float s1 = acc;
        #pragma unroll
        for (int m = 1; m < 16; m <<= 1) s1 += __shfl_xor(s1, m, 16);
        float mean = s1 * 0.0625f;
        float dv = acc - mean;
        float s2 = dv * dv;
        #pragma unroll
        for (int m = 1; m < 16; m <<= 1) s2 += __shfl_xor(s2, m, 16);
        qout[gtid] = dv * rsqrtf(s2 * 0.0625f + EPS) *
                     p.ln_g[(layer + 1) * 16 + d] + p.ln_b[(layer + 1) * 16 + d];
        return;
    }

    // ---- tail-block pattern: 256th arriver runs the epilogue ----
    __syncthreads();   // wave 0's s_waitcnt vmcnt(0) before barrier drains AG stores
    if (tid == 0) {
        int r = __hip_atomic_fetch_add(p.bar, 1, __ATOMIC_RELAXED,
                                       __HIP_MEMORY_SCOPE_AGENT);
        tailflag = (r == 255) ? 1 : 0;
    }
    __syncthreads();
    if (!tailflag) return;

    // ================= epilogue (tail block only) =================
    // stage 1: reduce 128 block-partials per (layer, graph, e)
    {
        int l = tid >> 7, bb = (tid >> 6) & 1, e = tid & 63;
        float mn = 1e30f, off = -1e30f, dg = -1e30f;
        for (int k = 0; k < 128; ++k) {
            int o = l * 16384 + (bb * 128 + k) * 64 + e;
            float vmn, voff, vdg;
            if (l == 3) { vmn = AG_LOAD(&p.Pmin[o]); voff = AG_LOAD(&p.Poff[o]); vdg = AG_LOAD(&p.Pdg[o]); }
            else        { vmn = p.Pmin[o];           voff = p.Poff[o];           vdg = p.Pdg[o]; }
            mn  = fminf(mn,  vmn);
            off = fmaxf(off, voff);
            dg  = fmaxf(dg,  vdg);
        }
        sm_mn[tid] = mn; sm_off[tid] = off; sm_dg[tid] = dg;
    }
    __syncthreads();
    // stage 2: per-layer val = |global max_diag - global min|
    if (tid < 4) {
        float gmx = -1e30f, gmn = 1e30f;
        for (int i2 = 0; i2 < 128; ++i2) {
            gmx = fmaxf(gmx, sm_dg[tid * 128 + i2]);
            gmn = fminf(gmn, sm_mn[tid * 128 + i2]);
        }
        vals[tid] = fabsf(gmx - gmn);
    }
    __syncthreads();
    // stage 3: partial GEMV  (tid = bb*256 + cc*8 + pp)
    {
        int bb = tid >> 8, cc = (tid >> 3) & 31, pp = tid & 7;
        float a2 = 0.0f;
        for (int l = 0; l < 4; ++l) {
            float val = vals[l];
            const float* Wr = p.opW + l * 4096 + cc * 128;
            int base = l * 128 + bb * 64;
            for (int j = pp * 16; j < pp * 16 + 16; ++j) {
                float pv;
                if (j < 64) pv = sm_dg[base + j];
                else        pv = fmaxf(sm_off[base + j - 64], sm_dg[base + j - 64] - val);
                a2 = fmaf(Wr[j], pv, a2);
            }
        }
        psum[tid] = a2;
    }
    __syncthreads();
    if (tid < 64) {
        int bb = tid >> 5, cc = tid & 31;
        float a2 = 0.0f;
        for (int l = 0; l < 4; ++l) a2 += p.opb[l * 32 + cc];
        for (int pp = 0; pp < 8; ++pp) a2 += psum[bb * 256 + cc * 8 + pp];
        scores_s[tid] = a2;
    }
    __syncthreads();
    if (tid < 32) {
        float sA = scores_s[tid], sB = scores_s[32 + tid];
        float mu2 = 0.5f * (sA + sB);
        float va = 0.5f * ((sA - mu2) * (sA - mu2) + (sB - mu2) * (sB - mu2));
        float inv = rsqrtf(va + EPS);
        p.out[tid]      = (sA - mu2) * inv;
        p.out[32 + tid] = (sB - mu2) * inv;
    }
}

// ---------------------------------------------------------------------------
extern "C" void kernel_launch(void* const* d_in, const int* in_sizes, int n_in,
                              void* d_out, int out_size, void* d_ws, size_t ws_size,
                              hipStream_t stream) {
    Params prm;
    prm.ei    = (const int*)d_in[0];
    prm.batch = (const int*)d_in[1];
    prm.E     = in_sizes[0] / 2;
    prm.W0    = (const float*)d_in[2];
    prm.b0    = (const float*)d_in[3];
    prm.Ws    = (const float*)d_in[4];
    prm.bs    = (const float*)d_in[5];
    prm.ln_g  = (const float*)d_in[6];
    prm.ln_b  = (const float*)d_in[7];
    prm.fW0   = (const float*)d_in[8];
    prm.fb0   = (const float*)d_in[9];
    prm.fWs   = (const float*)d_in[10];
    prm.fbs   = (const float*)d_in[11];
    prm.fln_g = (const float*)d_in[12];
    prm.fln_b = (const float*)d_in[13];
    prm.opW   = (const float*)d_in[14];
    prm.opb   = (const float*)d_in[15];

    float* ws = (float*)d_ws;
    prm.hA    = ws;                   // 131072 each
    prm.qA    = prm.hA   + 131072;
    prm.hB    = prm.qA   + 131072;
    prm.qB    = prm.hB   + 131072;
    prm.xbuf  = prm.qB   + 131072;
    prm.Pmin  = prm.xbuf + 131072;    // 4*16384 each
    prm.Poff  = prm.Pmin + 65536;
    prm.Pdg   = prm.Poff + 65536;
    prm.bar   = (int*)(prm.Pdg + 65536);
    prm.out   = (float*)d_out;

    k0<<<256, 512, 0, stream>>>(prm);
    klayer<<<256, 512, 0, stream>>>(prm, 1, 0);
    klayer<<<256, 512, 0, stream>>>(prm, 2, 0);
    klayer<<<256, 512, 0, stream>>>(prm, 3, 1);
}